// Round 2
// baseline (713.015 us; speedup 1.0000x reference)
//
#include <hip/hip_runtime.h>
#include <stdint.h>
#include <stddef.h>

// Problem constants (fixed by the reference).
constexpr int N_NODES = 10000;
constexpr int N_EDGES = 320000;
constexpr int DIM_IN  = 128;
constexpr int DIM_H   = 256;
constexpr int DIM_C   = 32;
constexpr int DIM_OUT = 64;
constexpr int DIM_QKV = DIM_C + DIM_C + DIM_H;  // 320 : [q|k|v]
constexpr int DIM_QK  = 2 * DIM_C;              // 64  : [q|k] compact fp32
constexpr int DIM_CAT = 2 * DIM_H;              // 512 : [h|comm]
constexpr float SCALE = 0.17677669529663687f;   // 1/sqrt(32)
constexpr int MAXD = 192;   // bucket capacity; Binomial(320k,1e-4) max ~66 (28 sigma margin)
constexpr float VSCALE = 64.0f;                 // fp8 v pre-scale (|v|max ~0.5 -> ~32 << 448)

// Persistent grid: 4 blocks/CU x 256 CUs. Co-residency guaranteed by resources:
// LDS 23,040 B (<= 160K/4=40K), VGPR capped at 128 via __launch_bounds__(256,4).
constexpr int NBLK = 1024;
constexpr int NTHR = 256;
constexpr int PAD  = 40;    // LDS row stride in bf16 (+8 pad: 2-way banks max, free)

#if __has_builtin(__builtin_amdgcn_cvt_pk_f32_fp8) && __has_builtin(__builtin_amdgcn_cvt_pk_fp8_f32)
#define V_FP8 1
#else
#define V_FP8 0   // fallback: bf16 v
#endif

// ---------------- workspace layout (4-byte words) ----------------
constexpr size_t alignw(size_t w) { return (w + 15) & ~size_t(15); }
constexpr size_t OFF_DEG   = 0;
constexpr size_t OFF_BAR   = OFF_DEG + N_NODES;                          // 1280 ints: barrier tree
constexpr size_t OFF_COL   = alignw(OFF_BAR + 1280);                     // [N][MAXD] bucket
constexpr size_t OFF_QK    = alignw(OFF_COL + (size_t)N_NODES * MAXD);   // fp32 [N][64]
constexpr size_t OFF_BQKV  = alignw(OFF_QK + (size_t)N_NODES * DIM_QK);
constexpr size_t OFF_VT    = alignw(OFF_BQKV + DIM_QKV);                        // [N][256] fp8/bf16
constexpr size_t OFF_XBF   = alignw(OFF_VT + (size_t)N_NODES * DIM_H / 2);      // [N][128]
constexpr size_t OFF_CATBF = alignw(OFF_XBF + (size_t)N_NODES * DIM_IN / 2);    // [N][512]
constexpr size_t OFF_WINT  = alignw(OFF_CATBF + (size_t)N_NODES * DIM_CAT / 2); // [256][128]
constexpr size_t OFF_WQKVT = alignw(OFF_WINT + (size_t)DIM_H * DIM_IN / 2);     // [320][256]
constexpr size_t OFF_W1T   = alignw(OFF_WQKVT + (size_t)DIM_QKV * DIM_H / 2);   // [256][512]
constexpr size_t OFF_W2T   = alignw(OFF_W1T + (size_t)DIM_H * DIM_CAT / 2);     // [64][256]

typedef __attribute__((ext_vector_type(8))) short short8;
typedef __attribute__((ext_vector_type(4))) float floatx4;
typedef __attribute__((ext_vector_type(2))) float floatx2;

#define MFMA16 __builtin_amdgcn_mfma_f32_16x16x32_bf16

__device__ inline unsigned short f2bf(float f) {
    uint32_t u = __builtin_bit_cast(uint32_t, f);
    uint32_t r = (u + 0x7fffu + ((u >> 16) & 1u)) >> 16;   // RNE
    return (unsigned short)r;
}
__device__ inline float bf2f_lo(uint32_t u) { return __builtin_bit_cast(float, u << 16); }
__device__ inline float bf2f_hi(uint32_t u) { return __builtin_bit_cast(float, u & 0xffff0000u); }

// Two-level device-scope barrier: 8 group counters (one cache line each, 128 blocks
// per group) feed one master line -> ~136 serialized same-line RMWs instead of 1024.
// Pollers only READ the master line (shareable); s_sleep(8) keeps poll traffic low.
__device__ inline void gbar(int* bar, int idx) {
    __syncthreads();
    if (threadIdx.x == 0) {
        __threadfence();
        const int g = blockIdx.x >> 7;                       // 8 groups x 128 blocks
        int* grp = bar + (idx * 9 + g) * 32;
        int* mst = bar + (idx * 9 + 8) * 32;
        if (__hip_atomic_fetch_add(grp, 1, __ATOMIC_RELEASE, __HIP_MEMORY_SCOPE_AGENT) == 127)
            __hip_atomic_fetch_add(mst, 1, __ATOMIC_RELEASE, __HIP_MEMORY_SCOPE_AGENT);
        while (__hip_atomic_load(mst, __ATOMIC_ACQUIRE, __HIP_MEMORY_SCOPE_AGENT) < 8)
            __builtin_amdgcn_s_sleep(8);
        __threadfence();
    }
    __syncthreads();
}

// =====================================================================================
// One persistent kernel; phases separated by grid barriers.
//   P1 prep -> P2 h=x@Win -> P3 qkv=h@Wqkv -> P4 sparse attention -> P5 relu(cat@W1)@W2
// Fine-grained GEMM jobs (628/785/313) so active blocks stack 2-4 deep per CU.
// =====================================================================================
__global__ __launch_bounds__(NTHR, 4)
void mega(const float* __restrict__ x, const int* __restrict__ ei,
          const float* __restrict__ W_in, const float* __restrict__ b_in,
          const float* __restrict__ Wq, const float* __restrict__ bq,
          const float* __restrict__ Wk, const float* __restrict__ bk,
          const float* __restrict__ Wv, const float* __restrict__ bv,
          const float* __restrict__ W1, const float* __restrict__ b1,
          const float* __restrict__ W2, const float* __restrict__ b2,
          float* __restrict__ out,
          int* __restrict__ deg, int* __restrict__ bar, int* __restrict__ col,
          float* __restrict__ qk, float* __restrict__ bqkv,
          unsigned short* __restrict__ v_tab, unsigned short* __restrict__ x_bf,
          unsigned short* __restrict__ cat_bf,
          unsigned short* __restrict__ WinT, unsigned short* __restrict__ WqkvT,
          unsigned short* __restrict__ W1T, unsigned short* __restrict__ W2T)
{
    __shared__ alignas(16) char SMEM[23040];
    const int tid   = threadIdx.x;
    const int bid   = blockIdx.x;
    const int wave  = tid >> 6;
    const int lane  = tid & 63;
    const int quad  = lane >> 4;
    const int col16 = lane & 15;
    const int sr    = tid >> 2;          // staging row 0..63
    const int sc    = (tid & 3) * 8;     // staging k-chunk (8 bf16 = 16B)

    // ---------------- P1: prep. Transposes: coalesced READ, scattered write. ----------
    {
        const int i0 = bid * NTHR + tid;
        const int stride = NBLK * NTHR;   // 262144
        for (int e = i0; e < N_EDGES; e += stride) {
            int src = ei[e];
            int dst = ei[N_EDGES + e];
            int slot = atomicAdd(&deg[src], 1);
            if (slot < MAXD) col[src * MAXD + slot] = dst;
        }
        for (int idx = i0; idx < (N_NODES * DIM_IN) / 8; idx += stride) {
            float4 a = ((const float4*)x)[2 * idx];
            float4 b = ((const float4*)x)[2 * idx + 1];
            uint4 o;
            o.x = (uint32_t)f2bf(a.x) | ((uint32_t)f2bf(a.y) << 16);
            o.y = (uint32_t)f2bf(a.z) | ((uint32_t)f2bf(a.w) << 16);
            o.z = (uint32_t)f2bf(b.x) | ((uint32_t)f2bf(b.y) << 16);
            o.w = (uint32_t)f2bf(b.z) | ((uint32_t)f2bf(b.w) << 16);
            ((uint4*)x_bf)[idx] = o;
        }
        for (int idx = i0; idx < DIM_IN * DIM_H; idx += stride) {    // W_in[128][256] -> WinT
            int k = idx >> 8, n = idx & 255;
            WinT[n * DIM_IN + k] = f2bf(W_in[idx]);
        }
        for (int idx = i0; idx < DIM_H * DIM_C; idx += stride) {     // Wq -> rows 0..31
            int k = idx >> 5, n = idx & 31;
            WqkvT[n * DIM_H + k] = f2bf(Wq[idx]);
        }
        for (int idx = i0; idx < DIM_H * DIM_C; idx += stride) {     // Wk -> rows 32..63
            int k = idx >> 5, n = idx & 31;
            WqkvT[(DIM_C + n) * DIM_H + k] = f2bf(Wk[idx]);
        }
        for (int idx = i0; idx < DIM_H * DIM_H; idx += stride) {     // Wv -> rows 64..319
            int k = idx >> 8, n = idx & 255;
            WqkvT[(2 * DIM_C + n) * DIM_H + k] = f2bf(Wv[idx]);
        }
        for (int idx = i0; idx < DIM_CAT * DIM_H; idx += stride) {   // W1[512][256] -> W1T
            int k = idx >> 8, n = idx & 255;
            W1T[n * DIM_CAT + k] = f2bf(W1[idx]);
        }
        for (int idx = i0; idx < DIM_H * DIM_OUT; idx += stride) {   // W2[256][64] -> W2T
            int k = idx >> 6, n = idx & 63;
            W2T[n * DIM_H + k] = f2bf(W2[idx]);
        }
        for (int idx = i0; idx < DIM_QKV; idx += stride)
            bqkv[idx] = (idx < DIM_C) ? bq[idx]
                      : (idx < 2 * DIM_C) ? bk[idx - DIM_C] : bv[idx - 2 * DIM_C];
    }
    gbar(bar, 0);

    // ---------------- P2: h = x @ WinT^T + b_in -> bf16 cat[:, 0:256] ----------------
    // 64x64 tiles -> 157*4 = 628 jobs; 4 waves each 32x32 (acc 2x2).
    {
        short* As = (short*)SMEM;              // 64 x PAD
        short* Bs = (short*)(SMEM + 5120);     // 64 x PAD
        if (bid < 157 * 4) {
            const int row0 = (bid >> 2) * 64;
            const int col0 = (bid & 3) * 64;
            const int wr = (wave >> 1) * 32, wc = (wave & 1) * 32;
            floatx4 acc[2][2] = {};
            for (int k0 = 0; k0 < DIM_IN; k0 += 32) {
                {
                    int gr = row0 + sr;
                    short8 v = {};
                    if (gr < N_NODES) v = *(const short8*)(x_bf + (size_t)gr * DIM_IN + k0 + sc);
                    *(short8*)(As + sr * PAD + sc) = v;
                }
                *(short8*)(Bs + sr * PAD + sc) =
                    *(const short8*)(WinT + (size_t)(col0 + sr) * DIM_IN + k0 + sc);
                __syncthreads();
                short8 af[2], bfr[2];
                #pragma unroll
                for (int m = 0; m < 2; ++m)
                    af[m] = *(const short8*)(As + (wr + m * 16 + col16) * PAD + quad * 8);
                #pragma unroll
                for (int n = 0; n < 2; ++n)
                    bfr[n] = *(const short8*)(Bs + (wc + n * 16 + col16) * PAD + quad * 8);
                #pragma unroll
                for (int m = 0; m < 2; ++m)
                    #pragma unroll
                    for (int n = 0; n < 2; ++n)
                        acc[m][n] = MFMA16(af[m], bfr[n], acc[m][n], 0, 0, 0);
                __syncthreads();
            }
            #pragma unroll
            for (int m = 0; m < 2; ++m)
                #pragma unroll
                for (int n = 0; n < 2; ++n) {
                    int gc = col0 + wc + n * 16 + col16;
                    float bia = b_in[gc];
                    #pragma unroll
                    for (int r = 0; r < 4; ++r) {
                        int gr = row0 + wr + m * 16 + quad * 4 + r;
                        if (gr < N_NODES)
                            cat_bf[(size_t)gr * DIM_CAT + gc] = f2bf(acc[m][n][r] + bia);
                    }
                }
        }
    }
    gbar(bar, 1);

    // ---------------- P3: qkv = h @ WqkvT^T + bqkv -> qk fp32 [N][64], v fp8 [N][256] --
    // 64x64 tiles -> 157*5 = 785 jobs; 4 waves each 32x32 (acc 2x2), K=256.
    {
        short* As = (short*)SMEM;
        short* Bs = (short*)(SMEM + 5120);
        if (bid < 157 * 5) {
            const int row0 = (bid / 5) * 64;
            const int col0 = (bid % 5) * 64;
            const int wr = (wave >> 1) * 32, wc = (wave & 1) * 32;
            floatx4 acc[2][2] = {};
            for (int k0 = 0; k0 < DIM_H; k0 += 32) {
                {
                    int gr = row0 + sr;
                    short8 v = {};
                    if (gr < N_NODES) v = *(const short8*)(cat_bf + (size_t)gr * DIM_CAT + k0 + sc);
                    *(short8*)(As + sr * PAD + sc) = v;
                }
                *(short8*)(Bs + sr * PAD + sc) =
                    *(const short8*)(WqkvT + (size_t)(col0 + sr) * DIM_H + k0 + sc);
                __syncthreads();
                short8 af[2], bfr[2];
                #pragma unroll
                for (int m = 0; m < 2; ++m)
                    af[m] = *(const short8*)(As + (wr + m * 16 + col16) * PAD + quad * 8);
                #pragma unroll
                for (int n = 0; n < 2; ++n)
                    bfr[n] = *(const short8*)(Bs + (wc + n * 16 + col16) * PAD + quad * 8);
                #pragma unroll
                for (int m = 0; m < 2; ++m)
                    #pragma unroll
                    for (int n = 0; n < 2; ++n)
                        acc[m][n] = MFMA16(af[m], bfr[n], acc[m][n], 0, 0, 0);
                __syncthreads();
            }
            #pragma unroll
            for (int m = 0; m < 2; ++m)
                #pragma unroll
                for (int n = 0; n < 2; ++n) {
                    int gc = col0 + wc + n * 16 + col16;
                    float bia = bqkv[gc];
                    #pragma unroll
                    for (int r = 0; r < 4; ++r) {
                        int gr = row0 + wr + m * 16 + quad * 4 + r;
                        if (gr >= N_NODES) continue;
                        float v = acc[m][n][r] + bia;
                        if (gc < DIM_QK) {
                            qk[(size_t)gr * DIM_QK + gc] = v;
                        } else {
#if V_FP8
                            int pk = __builtin_amdgcn_cvt_pk_fp8_f32(v * VSCALE, 0.f, 0, false);
                            ((unsigned char*)v_tab)[(size_t)gr * DIM_H + (gc - DIM_QK)] =
                                (unsigned char)(pk & 0xff);
#else
                            v_tab[(size_t)gr * DIM_H + (gc - DIM_QK)] = f2bf(v);
#endif
                        }
                    }
                }
        }
    }
    gbar(bar, 2);

    // ---------------- P4: fused per-row attention (dedup + softmax + v-gather) --------
    // 4096 waves, ~2.4 rows/wave; waves fully independent (wave-private LDS slices).
    {
        int*   dstW = (int*)SMEM + wave * MAXD;                     // [MAXD]
        float* wW   = (float*)(SMEM + 3072) + wave * MAXD;          // [MAXD]
        float* qW   = (float*)(SMEM + 6144) + wave * DIM_C;         // [32]
        for (int row = bid * 4 + wave; row < N_NODES; row += NBLK * 4) {
            __threadfence_block();               // prior-iter LDS reads done before overwrite
            int d = deg[row];
            if (d > MAXD) d = MAXD;
            const int* crow = col + (size_t)row * MAXD;

            for (int p = lane; p < d; p += 64) dstW[p] = crow[p];
            if (lane < DIM_C) qW[lane] = qk[(size_t)row * DIM_QK + lane];
            __threadfence_block();

            float mysum = 0.f;
            if (d <= 64) {
                int mydst = (lane < d) ? dstW[lane] : -1;
                bool dup = false;
                for (int k2 = 0; k2 < d - 1; ++k2) {
                    int other = __shfl(mydst, k2, 64);
                    dup = dup || (k2 < lane && other == mydst);
                }
                float w = 0.f;
                if (lane < d && !dup) {
                    const float4* kp = (const float4*)(qk + (size_t)mydst * DIM_QK + DIM_C);
                    float s = 0.f;
                    #pragma unroll
                    for (int i = 0; i < DIM_C / 4; ++i) {
                        float4 b = kp[i];
                        s += qW[4 * i + 0] * b.x + qW[4 * i + 1] * b.y
                           + qW[4 * i + 2] * b.z + qW[4 * i + 3] * b.w;
                    }
                    w = expf(s * SCALE);
                }
                wW[lane] = w;
                mysum = w;
            } else {
                for (int p = lane; p < d; p += 64) {
                    int mydst = dstW[p];
                    bool dup = false;
                    for (int j = 0; j < p; ++j) dup = dup || (dstW[j] == mydst);
                    float w = 0.f;
                    if (!dup) {
                        const float4* kp = (const float4*)(qk + (size_t)mydst * DIM_QK + DIM_C);
                        float s = 0.f;
                        #pragma unroll
                        for (int i = 0; i < DIM_C / 4; ++i) {
                            float4 b = kp[i];
                            s += qW[4 * i + 0] * b.x + qW[4 * i + 1] * b.y
                               + qW[4 * i + 2] * b.z + qW[4 * i + 3] * b.w;
                        }
                        w = expf(s * SCALE);
                    }
                    wW[p] = w;
                    mysum += w;
                }
            }
            #pragma unroll
            for (int off = 32; off; off >>= 1) mysum += __shfl_down(mysum, off, 64);
            float total = __shfl(mysum, 0, 64);
#if V_FP8
            float inv = (d > 0 && total > 0.f) ? 1.0f / (total * VSCALE) : 0.f;
#else
            float inv = (d > 0 && total > 0.f) ? 1.0f / total : 0.f;
#endif
            __threadfence_block();

            float4 acc = make_float4(0.f, 0.f, 0.f, 0.f);
#if V_FP8
            const uint32_t* vb = (const uint32_t*)v_tab;   // fp8 row = 64 dwords
#else
            const uint2* vb = (const uint2*)v_tab;         // bf16 row = 64 uint2
#endif
            for (int p0 = 0; p0 < d; p0 += 16) {
                int j[16]; float w[16];
                #pragma unroll
                for (int t = 0; t < 16; ++t) {
                    int idx = p0 + t;
                    bool in = idx < d;
                    j[t] = in ? dstW[idx] : 0;
                    w[t] = in ? wW[idx] : 0.f;
                }
#if V_FP8
                uint32_t r[16];
                #pragma unroll
                for (int t = 0; t < 16; ++t) r[t] = vb[(size_t)j[t] * 64 + lane];
                #pragma unroll
                for (int t = 0; t < 16; ++t) {
                    floatx2 lo = __builtin_amdgcn_cvt_pk_f32_fp8(r[t], false);
                    floatx2 hi = __builtin_amdgcn_cvt_pk_f32_fp8(r[t], true);
                    acc.x += w[t] * lo.x; acc.y += w[t] * lo.y;
                    acc.z += w[t] * hi.x; acc.w += w[t] * hi.y;
                }
#else
                uint2 r[16];
                #pragma unroll
                for (int t = 0; t < 16; ++t) r[t] = vb[(size_t)j[t] * 64 + lane];
                #pragma unroll
                for (int t = 0; t < 16; ++t) {
                    acc.x += w[t] * bf2f_lo(r[t].x);
                    acc.y += w[t] * bf2f_hi(r[t].x);
                    acc.z += w[t] * bf2f_lo(r[t].y);
                    acc.w += w[t] * bf2f_hi(r[t].y);
                }
#endif
            }
            acc.x *= inv; acc.y *= inv; acc.z *= inv; acc.w *= inv;
            uint2 o;
            o.x = (uint32_t)f2bf(acc.x) | ((uint32_t)f2bf(acc.y) << 16);
            o.y = (uint32_t)f2bf(acc.z) | ((uint32_t)f2bf(acc.w) << 16);
            *(uint2*)(cat_bf + (size_t)row * DIM_CAT + DIM_H + lane * 4) = o;
        }
    }
    gbar(bar, 3);

    // ---------------- P5: out = relu(cat@W1+b1)@W2 + b2 ----------------
    // BM=32 -> 313 jobs. Phase A: 4 waves each 32x64 (acc 2x4), z -> LDS (Ts aliases Bs).
    // Phase B: z @ W2T^T, each wave 32x16 (acc 2x1), K=256.
    {
        constexpr int TP = 260;
        short* As = (short*)SMEM;              // 32 x PAD  (2,560 B)
        short* Bs = (short*)(SMEM + 2560);     // 256 x PAD (20,480 B); Ts 32 x TP (16,640) aliases
        short* Ts = Bs;
        if (bid < 313) {
            const int row0 = bid * 32;
            floatx4 acc[2][4] = {};
            for (int k0 = 0; k0 < DIM_CAT; k0 += 32) {
                if (sr < 32) {
                    int gr = row0 + sr;
                    short8 v = {};
                    if (gr < N_NODES) v = *(const short8*)(cat_bf + (size_t)gr * DIM_CAT + k0 + sc);
                    *(short8*)(As + sr * PAD + sc) = v;
                }
                #pragma unroll
                for (int p = 0; p < 4; ++p) {
                    int r = sr + p * 64;
                    *(short8*)(Bs + r * PAD + sc) =
                        *(const short8*)(W1T + (size_t)r * DIM_CAT + k0 + sc);
                }
                __syncthreads();
                short8 af[2], bfr[4];
                #pragma unroll
                for (int m = 0; m < 2; ++m)
                    af[m] = *(const short8*)(As + (m * 16 + col16) * PAD + quad * 8);
                #pragma unroll
                for (int n = 0; n < 4; ++n)
                    bfr[n] = *(const short8*)(Bs + (wave * 64 + n * 16 + col16) * PAD + quad * 8);
                #pragma unroll
                for (int m = 0; m < 2; ++m)
                    #pragma unroll
                    for (int n = 0; n < 4; ++n)
                        acc[m][n] = MFMA16(af[m], bfr[n], acc[m][n], 0, 0, 0);
                __syncthreads();   // Bs reads done before next staging / Ts overwrite
            }
            // epilogue A: bias + relu -> bf16 z tile in Ts
            #pragma unroll
            for (int m = 0; m < 2; ++m)
                #pragma unroll
                for (int n = 0; n < 4; ++n) {
                    int gc = wave * 64 + n * 16 + col16;
                    float bia = b1[gc];
                    #pragma unroll
                    for (int r = 0; r < 4; ++r) {
                        int lr = m * 16 + quad * 4 + r;
                        Ts[lr * TP + gc] = (short)f2bf(fmaxf(acc[m][n][r] + bia, 0.f));
                    }
                }
            __syncthreads();
            // phase B: out = z @ W2T^T + b2, K=256; wave owns cols [wave*16, wave*16+16)
            floatx4 acc2[2] = {};
            for (int k0 = 0; k0 < DIM_H; k0 += 32) {
                short8 b = *(const short8*)(W2T + (size_t)(wave * 16 + col16) * DIM_H + k0 + quad * 8);
                #pragma unroll
                for (int m = 0; m < 2; ++m) {
                    short8 a = *(const short8*)(Ts + (m * 16 + col16) * TP + k0 + quad * 8);
                    acc2[m] = MFMA16(a, b, acc2[m], 0, 0, 0);
                }
            }
            #pragma unroll
            for (int m = 0; m < 2; ++m) {
                int gc = wave * 16 + col16;
                float bia = b2[gc];
                #pragma unroll
                for (int r = 0; r < 4; ++r) {
                    int gr = row0 + m * 16 + quad * 4 + r;
                    if (gr < N_NODES) out[(size_t)gr * DIM_OUT + gc] = acc2[m][r] + bia;
                }
            }
        }
    }
}

// ---------------- launcher ----------------
extern "C" void kernel_launch(void* const* d_in, const int* in_sizes, int n_in,
                              void* d_out, int out_size, void* d_ws, size_t ws_size,
                              hipStream_t stream) {
    (void)in_sizes; (void)n_in; (void)out_size; (void)ws_size;
    const float* x    = (const float*)d_in[0];
    const int*   ei   = (const int*)d_in[1];
    const float* W_in = (const float*)d_in[2];
    const float* b_in = (const float*)d_in[3];
    const float* Wq   = (const float*)d_in[4];
    const float* bq   = (const float*)d_in[5];
    const float* Wk   = (const float*)d_in[6];
    const float* bk   = (const float*)d_in[7];
    const float* Wv   = (const float*)d_in[8];
    const float* bv   = (const float*)d_in[9];
    const float* W1   = (const float*)d_in[10];
    const float* b1   = (const float*)d_in[11];
    const float* W2   = (const float*)d_in[12];
    const float* b2   = (const float*)d_in[13];
    float* out = (float*)d_out;

    uint32_t* ws      = (uint32_t*)d_ws;
    int*      deg     = (int*)(ws + OFF_DEG);
    int*      bar     = (int*)(ws + OFF_BAR);
    int*      col     = (int*)(ws + OFF_COL);
    float*    qk      = (float*)(ws + OFF_QK);
    float*    bqkv    = (float*)(ws + OFF_BQKV);
    unsigned short* v_tab  = (unsigned short*)(ws + OFF_VT);
    unsigned short* x_bf   = (unsigned short*)(ws + OFF_XBF);
    unsigned short* cat_bf = (unsigned short*)(ws + OFF_CATBF);
    unsigned short* WinT   = (unsigned short*)(ws + OFF_WINT);
    unsigned short* WqkvT  = (unsigned short*)(ws + OFF_WQKVT);
    unsigned short* W1T    = (unsigned short*)(ws + OFF_W1T);
    unsigned short* W2T    = (unsigned short*)(ws + OFF_W2T);

    // zero deg + barrier tree (45 KB), then the persistent megakernel
    hipMemsetAsync(ws, 0, (OFF_BAR + 1280) * sizeof(uint32_t), stream);
    hipLaunchKernelGGL(mega, dim3(NBLK), dim3(NTHR), 0, stream,
                       x, ei, W_in, b_in, Wq, bq, Wk, bk, Wv, bv, W1, b1, W2, b2, out,
                       deg, bar, col, qk, bqkv, v_tab, x_bf, cat_bf,
                       WinT, WqkvT, W1T, W2T);
}

// Round 3
// 189.266 us; speedup vs baseline: 3.7673x; 3.7673x over previous
//
#include <hip/hip_runtime.h>
#include <stdint.h>
#include <stddef.h>

// Problem constants (fixed by the reference).
constexpr int N_NODES = 10000;
constexpr int N_EDGES = 320000;
constexpr int DIM_IN  = 128;
constexpr int DIM_H   = 256;
constexpr int DIM_C   = 32;
constexpr int DIM_OUT = 64;
constexpr int DIM_QKV = DIM_C + DIM_C + DIM_H;  // 320 : [q|k|v]
constexpr int DIM_QK  = 2 * DIM_C;              // 64  : [q|k] compact fp32
constexpr int DIM_CAT = 2 * DIM_H;              // 512 : [h|comm]
constexpr float SCALE = 0.17677669529663687f;   // 1/sqrt(32)
constexpr int MAXD = 192;   // bucket capacity; Binomial(320k,1e-4) max ~66 (28 sigma margin)
constexpr float VSCALE = 64.0f;                 // fp8 v pre-scale (|v|max ~0.5 -> ~32 << 448)
constexpr int PAD = 40;     // LDS row stride (bf16): 80B rows, 16B-aligned, 2-way banks max
constexpr int HP  = 264;    // h-tile LDS row stride: 528B rows, 16B-aligned, 2-way banks

#if __has_builtin(__builtin_amdgcn_cvt_pk_f32_fp8) && __has_builtin(__builtin_amdgcn_cvt_pk_fp8_f32)
#define V_FP8 1
#else
#define V_FP8 0   // fallback: bf16 v
#endif

// ---------------- workspace layout (4-byte words) ----------------
constexpr size_t alignw(size_t w) { return (w + 15) & ~size_t(15); }
constexpr size_t OFF_DEG   = 0;
constexpr size_t OFF_COL   = alignw(OFF_DEG + N_NODES);                  // [N][MAXD] bucket
constexpr size_t OFF_QK    = alignw(OFF_COL + (size_t)N_NODES * MAXD);   // fp32 [N][64]
constexpr size_t OFF_BQKV  = alignw(OFF_QK + (size_t)N_NODES * DIM_QK);
constexpr size_t OFF_VT    = alignw(OFF_BQKV + DIM_QKV);                        // [N][256] fp8/bf16
constexpr size_t OFF_CATBF = alignw(OFF_VT + (size_t)N_NODES * DIM_H / 2);      // [N][512]
constexpr size_t OFF_WINT  = alignw(OFF_CATBF + (size_t)N_NODES * DIM_CAT / 2); // [256][128]
constexpr size_t OFF_WQKVT = alignw(OFF_WINT + (size_t)DIM_H * DIM_IN / 2);     // [320][256]
constexpr size_t OFF_W1T   = alignw(OFF_WQKVT + (size_t)DIM_QKV * DIM_H / 2);   // [256][512]
constexpr size_t OFF_W2T   = alignw(OFF_W1T + (size_t)DIM_H * DIM_CAT / 2);     // [64][256]

typedef __attribute__((ext_vector_type(8))) short short8;
typedef __attribute__((ext_vector_type(4))) float floatx4;
typedef __attribute__((ext_vector_type(2))) float floatx2;

#define MFMA16 __builtin_amdgcn_mfma_f32_16x16x32_bf16

__device__ inline unsigned short f2bf(float f) {
    uint32_t u = __builtin_bit_cast(uint32_t, f);
    uint32_t r = (u + 0x7fffu + ((u >> 16) & 1u)) >> 16;   // RNE
    return (unsigned short)r;
}
__device__ inline float bf2f_lo(uint32_t u) { return __builtin_bit_cast(float, u << 16); }
__device__ inline float bf2f_hi(uint32_t u) { return __builtin_bit_cast(float, u & 0xffff0000u); }

// ---------------- prep: edge bucket-scatter + weight transpose/cast + bias concat -----
// Transposes read COALESCED from the f32 source, write scattered u16 (L2 merges).
__global__ void prep(const int* __restrict__ ei,
                     const float* __restrict__ W_in,
                     const float* __restrict__ Wq, const float* __restrict__ Wk,
                     const float* __restrict__ Wv,
                     const float* __restrict__ bq, const float* __restrict__ bk,
                     const float* __restrict__ bv,
                     const float* __restrict__ W1, const float* __restrict__ W2,
                     int* __restrict__ deg, int* __restrict__ col,
                     unsigned short* __restrict__ WinT, unsigned short* __restrict__ WqkvT,
                     unsigned short* __restrict__ W1T, unsigned short* __restrict__ W2T,
                     float* __restrict__ bqkv)
{
    const int i0 = blockIdx.x * blockDim.x + threadIdx.x;
    const int stride = gridDim.x * blockDim.x;
    for (int e = i0; e < N_EDGES; e += stride) {
        int src = ei[e];
        int dst = ei[N_EDGES + e];
        int slot = atomicAdd(&deg[src], 1);
        if (slot < MAXD) col[src * MAXD + slot] = dst;
    }
    for (int idx = i0; idx < DIM_IN * DIM_H; idx += stride) {    // W_in[128][256]
        int k = idx >> 8, n = idx & 255;
        WinT[n * DIM_IN + k] = f2bf(W_in[idx]);
    }
    for (int idx = i0; idx < DIM_H * DIM_C; idx += stride) {     // Wq[256][32] -> rows 0..31
        int k = idx >> 5, n = idx & 31;
        WqkvT[n * DIM_H + k] = f2bf(Wq[idx]);
    }
    for (int idx = i0; idx < DIM_H * DIM_C; idx += stride) {     // Wk -> rows 32..63
        int k = idx >> 5, n = idx & 31;
        WqkvT[(DIM_C + n) * DIM_H + k] = f2bf(Wk[idx]);
    }
    for (int idx = i0; idx < DIM_H * DIM_H; idx += stride) {     // Wv[256][256] -> rows 64..319
        int k = idx >> 8, n = idx & 255;
        WqkvT[(2 * DIM_C + n) * DIM_H + k] = f2bf(Wv[idx]);
    }
    for (int idx = i0; idx < DIM_CAT * DIM_H; idx += stride) {   // W1[512][256]
        int k = idx >> 8, n = idx & 255;
        W1T[n * DIM_CAT + k] = f2bf(W1[idx]);
    }
    for (int idx = i0; idx < DIM_H * DIM_OUT; idx += stride) {   // W2[256][64]
        int k = idx >> 6, n = idx & 63;
        W2T[n * DIM_H + k] = f2bf(W2[idx]);
    }
    for (int idx = i0; idx < DIM_QKV; idx += stride)
        bqkv[idx] = (idx < DIM_C) ? bq[idx]
                  : (idx < 2 * DIM_C) ? bk[idx - DIM_C] : bv[idx - 2 * DIM_C];
}

// ---------------- fused GEMM1+GEMM2: h = x@Win+b (LDS-resident) then qkv = h@Wqkv+b ----
// One block per 64-row strip (157 blocks). h computed once, consumed from LDS for qkv
// (no global round-trip before attention). x cast f32->bf16 inline during A-staging.
// LDS: hS 64x264 (33.8 KB) + Bs 320x40 (25.6 KB, phase-1 aliases x-tile into rows 256+).
__global__ __launch_bounds__(256)
void gemm12(const float* __restrict__ x,
            const unsigned short* __restrict__ WinT, const float* __restrict__ b_in,
            const unsigned short* __restrict__ WqkvT, const float* __restrict__ bqkv,
            unsigned short* __restrict__ cat_bf, float* __restrict__ qk,
            unsigned short* __restrict__ v_tab)
{
    __shared__ short hS[64 * HP];       // 33,792 B
    __shared__ short Bs[320 * PAD];     // 25,600 B; phase-1: rows 0..255 = WinT tile,
    short* As = Bs + 256 * PAD;         //           rows 256..319 = x tile (64 x 32)
    const int tid   = threadIdx.x;
    const int wave  = tid >> 6;
    const int lane  = tid & 63;
    const int quad  = lane >> 4;
    const int col16 = lane & 15;
    const int sr    = tid >> 2;          // staging row 0..63
    const int sc    = (tid & 3) * 8;     // staging k-chunk (8 bf16 = 16B)
    const int row0  = blockIdx.x * 64;

    // ---- phase 1: h = x @ WinT^T + b_in  (K=128, BN=256; wave w owns rows w*16..+16) --
    floatx4 acc[16] = {};
    for (int k0 = 0; k0 < DIM_IN; k0 += 32) {
        {   // x tile 64x32: load f32, cast inline
            int gr = row0 + sr;
            float4 a = {}, b = {};
            if (gr < N_NODES) {
                const float4* xp = (const float4*)(x + (size_t)gr * DIM_IN + k0 + sc);
                a = xp[0]; b = xp[1];
            }
            uint4 o;
            o.x = (uint32_t)f2bf(a.x) | ((uint32_t)f2bf(a.y) << 16);
            o.y = (uint32_t)f2bf(a.z) | ((uint32_t)f2bf(a.w) << 16);
            o.z = (uint32_t)f2bf(b.x) | ((uint32_t)f2bf(b.y) << 16);
            o.w = (uint32_t)f2bf(b.z) | ((uint32_t)f2bf(b.w) << 16);
            *(uint4*)(As + sr * PAD + sc) = o;
        }
        #pragma unroll
        for (int p = 0; p < 4; ++p) {   // WinT tile 256x32
            int r = sr + p * 64;
            *(short8*)(Bs + r * PAD + sc) = *(const short8*)(WinT + (size_t)r * DIM_IN + k0 + sc);
        }
        __syncthreads();
        short8 af = *(const short8*)(As + (wave * 16 + col16) * PAD + quad * 8);
        #pragma unroll
        for (int nf = 0; nf < 16; ++nf) {
            short8 bf = *(const short8*)(Bs + (nf * 16 + col16) * PAD + quad * 8);
            acc[nf] = MFMA16(af, bf, acc[nf], 0, 0, 0);
        }
        __syncthreads();
    }
    // epilogue 1: bias -> bf16 -> hS (LDS) + cat_bf[:, 0:256] (global, for w1w2)
    #pragma unroll
    for (int nf = 0; nf < 16; ++nf) {
        int gc = nf * 16 + col16;
        float bia = b_in[gc];
        #pragma unroll
        for (int r = 0; r < 4; ++r) {
            int lr = wave * 16 + quad * 4 + r;
            unsigned short hv = f2bf(acc[nf][r] + bia);
            hS[lr * HP + gc] = (short)hv;
            if (row0 + lr < N_NODES) cat_bf[(size_t)(row0 + lr) * DIM_CAT + gc] = hv;
        }
    }
    __syncthreads();

    // ---- phase 2: qkv = h @ WqkvT^T + bqkv  (K=256, BN=320; A-frags straight from hS) --
    floatx4 acc2[20] = {};
    for (int k0 = 0; k0 < DIM_H; k0 += 32) {
        #pragma unroll
        for (int p = 0; p < 5; ++p) {   // WqkvT tile 320x32
            int r = sr + p * 64;
            *(short8*)(Bs + r * PAD + sc) = *(const short8*)(WqkvT + (size_t)r * DIM_H + k0 + sc);
        }
        __syncthreads();
        short8 af = *(const short8*)(hS + (wave * 16 + col16) * HP + k0 + quad * 8);
        #pragma unroll
        for (int nf = 0; nf < 20; ++nf) {
            short8 bf = *(const short8*)(Bs + (nf * 16 + col16) * PAD + quad * 8);
            acc2[nf] = MFMA16(af, bf, acc2[nf], 0, 0, 0);
        }
        __syncthreads();
    }
    // epilogue 2: split -> qk fp32 [N][64], v fp8/bf16 [N][256]
    #pragma unroll
    for (int nf = 0; nf < 20; ++nf) {
        int gc = nf * 16 + col16;
        float bia = bqkv[gc];
        #pragma unroll
        for (int r = 0; r < 4; ++r) {
            int gr = row0 + wave * 16 + quad * 4 + r;
            if (gr >= N_NODES) continue;
            float v = acc2[nf][r] + bia;
            if (gc < DIM_QK) {
                qk[(size_t)gr * DIM_QK + gc] = v;
            } else {
#if V_FP8
                int pk = __builtin_amdgcn_cvt_pk_fp8_f32(v * VSCALE, 0.f, 0, false);
                ((unsigned char*)v_tab)[(size_t)gr * DIM_H + (gc - DIM_QK)] =
                    (unsigned char)(pk & 0xff);
#else
                v_tab[(size_t)gr * DIM_H + (gc - DIM_QK)] = f2bf(v);
#endif
            }
        }
    }
}

// ---------------- fused per-row attention: dedup + softmax + weighted v-gather --------
// One wave per row, 4 rows per block (2500 blocks). Proven round-0 structure.
__global__ __launch_bounds__(256)
void attn_row(const float* __restrict__ qk, const unsigned short* __restrict__ v_tab,
              const int* __restrict__ deg, const int* __restrict__ col,
              unsigned short* __restrict__ cat_bf) {
    __shared__ int   dstS[4][MAXD];
    __shared__ float wS[4][MAXD];
    __shared__ float qS[4][DIM_C];
    const int wave = threadIdx.x >> 6;
    const int lane = threadIdx.x & 63;
    const int row = blockIdx.x * 4 + wave;   // grid is exactly N_NODES/4
    int d = deg[row];
    if (d > MAXD) d = MAXD;
    const int* crow = col + (size_t)row * MAXD;

    for (int p = lane; p < d; p += 64) dstS[wave][p] = crow[p];
    if (lane < DIM_C) qS[wave][lane] = qk[(size_t)row * DIM_QK + lane];
    __syncthreads();

    float mysum = 0.f;
    if (d <= 64) {
        int mydst = (lane < d) ? dstS[wave][lane] : -1;
        bool dup = false;
        for (int k2 = 0; k2 < d - 1; ++k2) {            // dynamic bound (~31 iters avg)
            int other = __shfl(mydst, k2, 64);
            dup = dup || (k2 < lane && other == mydst);
        }
        float w = 0.f;
        if (lane < d && !dup) {
            const float4* kp = (const float4*)(qk + (size_t)mydst * DIM_QK + DIM_C);
            float s = 0.f;
            #pragma unroll
            for (int i = 0; i < DIM_C / 4; ++i) {
                float4 b = kp[i];
                s += qS[wave][4 * i + 0] * b.x + qS[wave][4 * i + 1] * b.y
                   + qS[wave][4 * i + 2] * b.z + qS[wave][4 * i + 3] * b.w;
            }
            w = expf(s * SCALE);
        }
        wS[wave][lane] = w;
        mysum = w;
    } else {
        for (int p = lane; p < d; p += 64) {
            int mydst = dstS[wave][p];
            bool dup = false;
            for (int j = 0; j < p; ++j) dup = dup || (dstS[wave][j] == mydst);
            float w = 0.f;
            if (!dup) {
                const float4* kp = (const float4*)(qk + (size_t)mydst * DIM_QK + DIM_C);
                float s = 0.f;
                #pragma unroll
                for (int i = 0; i < DIM_C / 4; ++i) {
                    float4 b = kp[i];
                    s += qS[wave][4 * i + 0] * b.x + qS[wave][4 * i + 1] * b.y
                       + qS[wave][4 * i + 2] * b.z + qS[wave][4 * i + 3] * b.w;
                }
                w = expf(s * SCALE);
            }
            wS[wave][p] = w;
            mysum += w;
        }
    }
    #pragma unroll
    for (int off = 32; off; off >>= 1) mysum += __shfl_down(mysum, off, 64);
    float total = __shfl(mysum, 0, 64);
#if V_FP8
    float inv = (d > 0 && total > 0.f) ? 1.0f / (total * VSCALE) : 0.f;
#else
    float inv = (d > 0 && total > 0.f) ? 1.0f / total : 0.f;
#endif
    __syncthreads();

    float4 acc = make_float4(0.f, 0.f, 0.f, 0.f);
#if V_FP8
    const uint32_t* vb = (const uint32_t*)v_tab;     // fp8 row = 64 dwords
#else
    const uint2* vb = (const uint2*)v_tab;           // bf16 row = 64 uint2
#endif
    for (int p0 = 0; p0 < d; p0 += 16) {
        int j[16]; float w[16];
        #pragma unroll
        for (int t = 0; t < 16; ++t) {
            int idx = p0 + t;
            bool in = idx < d;
            j[t] = in ? dstS[wave][idx] : 0;        // pad: row 0 (L2-hot), weight 0
            w[t] = in ? wS[wave][idx] : 0.f;
        }
#if V_FP8
        uint32_t r[16];
        #pragma unroll
        for (int t = 0; t < 16; ++t) r[t] = vb[(size_t)j[t] * 64 + lane];
        #pragma unroll
        for (int t = 0; t < 16; ++t) {
            floatx2 lo = __builtin_amdgcn_cvt_pk_f32_fp8(r[t], false);
            floatx2 hi = __builtin_amdgcn_cvt_pk_f32_fp8(r[t], true);
            acc.x += w[t] * lo.x; acc.y += w[t] * lo.y;
            acc.z += w[t] * hi.x; acc.w += w[t] * hi.y;
        }
#else
        uint2 r[16];
        #pragma unroll
        for (int t = 0; t < 16; ++t) r[t] = vb[(size_t)j[t] * 64 + lane];
        #pragma unroll
        for (int t = 0; t < 16; ++t) {
            acc.x += w[t] * bf2f_lo(r[t].x);
            acc.y += w[t] * bf2f_hi(r[t].x);
            acc.z += w[t] * bf2f_lo(r[t].y);
            acc.w += w[t] * bf2f_hi(r[t].y);
        }
#endif
    }
    acc.x *= inv; acc.y *= inv; acc.z *= inv; acc.w *= inv;
    uint2 o;
    o.x = (uint32_t)f2bf(acc.x) | ((uint32_t)f2bf(acc.y) << 16);
    o.y = (uint32_t)f2bf(acc.z) | ((uint32_t)f2bf(acc.w) << 16);
    *(uint2*)(cat_bf + (size_t)row * DIM_CAT + DIM_H + lane * 4) = o;
}

// ---------------- fused W1(relu) + W2 GEMM: out = relu(cat@W1+b1)@W2 + b2 -------------
// Proven round-0 structure. BM=64, z (64x256) never leaves the CU.
__global__ __launch_bounds__(256)
void gemm_w1w2(const unsigned short* __restrict__ cat, const unsigned short* __restrict__ W1T,
               const float* __restrict__ b1, const unsigned short* __restrict__ W2T,
               const float* __restrict__ b2, float* __restrict__ out, int M)
{
    constexpr int TP = 260;   // Ts row stride (bf16)
    __shared__ short As[64 * PAD];                 // 5,120 B
    __shared__ short BsTs[64 * TP];                // 33,280 B: Bs (256*40=10,240 sh) aliases Ts
    short* Bs = BsTs;
    short* Ts = BsTs;
    const int tid   = threadIdx.x;
    const int wave  = tid >> 6;
    const int lane  = tid & 63;
    const int quad  = lane >> 4;
    const int col16 = lane & 15;
    const int row0  = blockIdx.x * 64;

    const int sr = tid >> 2;          // 0..63
    const int sc = (tid & 3) * 8;     // 16B k-chunk

    // ---- phase A: z = relu(cat @ W1T^T + b1), 64 rows x 256 cols ----
    floatx4 acc[16] = {};
    for (int k0 = 0; k0 < DIM_CAT; k0 += 32) {
        {   // A tile: 64 rows x 32 k
            int gr = row0 + sr;
            short8 v = {};
            if (gr < M) v = *(const short8*)(cat + (size_t)gr * DIM_CAT + k0 + sc);
            *(short8*)(As + sr * PAD + sc) = v;
        }
        #pragma unroll
        for (int p = 0; p < 4; ++p) {  // B tile: 256 n-rows x 32 k
            int r = sr + p * 64;
            *(short8*)(Bs + r * PAD + sc) = *(const short8*)(W1T + (size_t)r * DIM_CAT + k0 + sc);
        }
        __syncthreads();
        short8 a = *(const short8*)(As + (wave * 16 + col16) * PAD + quad * 8);
        #pragma unroll
        for (int nf = 0; nf < 16; ++nf) {
            short8 b = *(const short8*)(Bs + (nf * 16 + col16) * PAD + quad * 8);
            acc[nf] = MFMA16(a, b, acc[nf], 0, 0, 0);
        }
        __syncthreads();   // all Bs reads done before next staging (and before Ts overwrite)
    }

    // epilogue A: bias + relu -> bf16 z tile in Ts (aliases Bs; safe after final barrier)
    #pragma unroll
    for (int nf = 0; nf < 16; ++nf) {
        int gc = nf * 16 + col16;
        float bia = b1[gc];
        #pragma unroll
        for (int r = 0; r < 4; ++r) {
            int lr = wave * 16 + quad * 4 + r;
            float v = fmaxf(acc[nf][r] + bia, 0.f);
            Ts[lr * TP + gc] = (short)f2bf(v);
        }
    }
    __syncthreads();

    // ---- phase B: out = z @ W2T^T + b2, K=256, N=64 ----
    floatx4 acc2[4] = {};
    for (int k0 = 0; k0 < DIM_H; k0 += 32) {
        short8 a = *(const short8*)(Ts + (wave * 16 + col16) * TP + k0 + quad * 8);
        #pragma unroll
        for (int nf = 0; nf < 4; ++nf) {
            int brow = nf * 16 + col16;
            short8 b = *(const short8*)(W2T + (size_t)brow * DIM_H + k0 + quad * 8);
            acc2[nf] = MFMA16(a, b, acc2[nf], 0, 0, 0);
        }
    }
    #pragma unroll
    for (int nf = 0; nf < 4; ++nf) {
        int gc = nf * 16 + col16;
        float bia = b2[gc];
        #pragma unroll
        for (int r = 0; r < 4; ++r) {
            int gr = row0 + wave * 16 + quad * 4 + r;
            if (gr < M) out[(size_t)gr * DIM_OUT + gc] = acc2[nf][r] + bia;
        }
    }
}

// ---------------- launcher ----------------
extern "C" void kernel_launch(void* const* d_in, const int* in_sizes, int n_in,
                              void* d_out, int out_size, void* d_ws, size_t ws_size,
                              hipStream_t stream) {
    (void)in_sizes; (void)n_in; (void)out_size; (void)ws_size;
    const float* x    = (const float*)d_in[0];
    const int*   ei   = (const int*)d_in[1];
    const float* W_in = (const float*)d_in[2];
    const float* b_in = (const float*)d_in[3];
    const float* Wq   = (const float*)d_in[4];
    const float* bq   = (const float*)d_in[5];
    const float* Wk   = (const float*)d_in[6];
    const float* bk   = (const float*)d_in[7];
    const float* Wv   = (const float*)d_in[8];
    const float* bv   = (const float*)d_in[9];
    const float* W1   = (const float*)d_in[10];
    const float* b1   = (const float*)d_in[11];
    const float* W2   = (const float*)d_in[12];
    const float* b2   = (const float*)d_in[13];
    float* out = (float*)d_out;

    uint32_t* ws      = (uint32_t*)d_ws;
    int*      deg     = (int*)(ws + OFF_DEG);
    int*      col     = (int*)(ws + OFF_COL);
    float*    qk      = (float*)(ws + OFF_QK);
    float*    bqkv    = (float*)(ws + OFF_BQKV);
    unsigned short* v_tab  = (unsigned short*)(ws + OFF_VT);
    unsigned short* cat_bf = (unsigned short*)(ws + OFF_CATBF);
    unsigned short* WinT   = (unsigned short*)(ws + OFF_WINT);
    unsigned short* WqkvT  = (unsigned short*)(ws + OFF_WQKVT);
    unsigned short* W1T    = (unsigned short*)(ws + OFF_W1T);
    unsigned short* W2T    = (unsigned short*)(ws + OFF_W2T);

    // 0) zero deg (40 KB) + fused prep (edges + weight transposes + bias concat)
    hipMemsetAsync(deg, 0, N_NODES * sizeof(int), stream);
    prep<<<640, 256, 0, stream>>>(ei, W_in, Wq, Wk, Wv, bq, bk, bv, W1, W2,
                                  deg, col, WinT, WqkvT, W1T, W2T, bqkv);
    // 1+2) fused h-GEMM + qkv-GEMM (h LDS-resident per 64-row strip)
    gemm12<<<(N_NODES + 63) / 64, 256, 0, stream>>>(
        x, WinT, b_in, WqkvT, bqkv, cat_bf, qk, v_tab);
    // 3) fused sparse attention (dedup + softmax + v-gather)
    attn_row<<<N_NODES / 4, 256, 0, stream>>>(qk, v_tab, deg, col, cat_bf);
    // 4+5) out = relu(cat@W1+b1)@W2 + b2, z kept on-CU
    gemm_w1w2<<<(N_NODES + 63) / 64, 256, 0, stream>>>(
        cat_bf, W1T, b1, W2T, b2, out, N_NODES);
}

// Round 4
// 168.823 us; speedup vs baseline: 4.2234x; 1.1211x over previous
//
#include <hip/hip_runtime.h>
#include <stdint.h>
#include <stddef.h>

// Problem constants (fixed by the reference).
constexpr int N_NODES = 10000;
constexpr int N_EDGES = 320000;
constexpr int DIM_IN  = 128;
constexpr int DIM_H   = 256;
constexpr int DIM_C   = 32;
constexpr int DIM_OUT = 64;
constexpr int DIM_QKV = DIM_C + DIM_C + DIM_H;  // 320 : [q|k|v]
constexpr int DIM_QK  = 2 * DIM_C;              // 64  : [q|k] compact fp32
constexpr int DIM_CAT = 2 * DIM_H;              // 512 : [h|comm]
constexpr float SCALE = 0.17677669529663687f;   // 1/sqrt(32)
constexpr int MAXD = 192;   // bucket capacity; Binomial(320k,1e-4) max ~66 (28 sigma margin)
constexpr float VSCALE = 64.0f;                 // fp8 v pre-scale (|v|max ~0.5 -> ~32 << 448)
constexpr int PAD = 40;     // LDS row stride (bf16): 80B rows, 16B-aligned, 2-way banks max
constexpr int HP  = 264;    // h-tile LDS row stride: 528B rows, 16B-aligned, 2-way banks

#if __has_builtin(__builtin_amdgcn_cvt_pk_f32_fp8) && __has_builtin(__builtin_amdgcn_cvt_pk_fp8_f32)
#define V_FP8 1
#else
#define V_FP8 0   // fallback: bf16 v
#endif

// ---------------- workspace layout (4-byte words) ----------------
constexpr size_t alignw(size_t w) { return (w + 15) & ~size_t(15); }
constexpr size_t OFF_DEG   = 0;
constexpr size_t OFF_COL   = alignw(OFF_DEG + N_NODES);                  // [N][MAXD] bucket
constexpr size_t OFF_QK    = alignw(OFF_COL + (size_t)N_NODES * MAXD);   // fp32 [N][64]
constexpr size_t OFF_BQKV  = alignw(OFF_QK + (size_t)N_NODES * DIM_QK);
constexpr size_t OFF_VT    = alignw(OFF_BQKV + DIM_QKV);                        // [N][256] fp8/bf16
constexpr size_t OFF_CATBF = alignw(OFF_VT + (size_t)N_NODES * DIM_H / 2);      // [N][512]
constexpr size_t OFF_WINT  = alignw(OFF_CATBF + (size_t)N_NODES * DIM_CAT / 2); // [256][128]
constexpr size_t OFF_WQKVT = alignw(OFF_WINT + (size_t)DIM_H * DIM_IN / 2);     // [320][256]
constexpr size_t OFF_W1T   = alignw(OFF_WQKVT + (size_t)DIM_QKV * DIM_H / 2);   // [256][512]
constexpr size_t OFF_W2T   = alignw(OFF_W1T + (size_t)DIM_H * DIM_CAT / 2);     // [64][256]

typedef __attribute__((ext_vector_type(8))) short short8;
typedef __attribute__((ext_vector_type(4))) float floatx4;
typedef __attribute__((ext_vector_type(2))) float floatx2;

#define MFMA16 __builtin_amdgcn_mfma_f32_16x16x32_bf16

__device__ inline unsigned short f2bf(float f) {
    uint32_t u = __builtin_bit_cast(uint32_t, f);
    uint32_t r = (u + 0x7fffu + ((u >> 16) & 1u)) >> 16;   // RNE
    return (unsigned short)r;
}
__device__ inline float bf2f_lo(uint32_t u) { return __builtin_bit_cast(float, u << 16); }
__device__ inline float bf2f_hi(uint32_t u) { return __builtin_bit_cast(float, u & 0xffff0000u); }

// ---------------- prep: edge bucket-scatter + weight transpose/cast + bias concat -----
// Transposes read COALESCED from the f32 source, write scattered u16 (L2 merges).
__global__ void prep(const int* __restrict__ ei,
                     const float* __restrict__ W_in,
                     const float* __restrict__ Wq, const float* __restrict__ Wk,
                     const float* __restrict__ Wv,
                     const float* __restrict__ bq, const float* __restrict__ bk,
                     const float* __restrict__ bv,
                     const float* __restrict__ W1, const float* __restrict__ W2,
                     int* __restrict__ deg, int* __restrict__ col,
                     unsigned short* __restrict__ WinT, unsigned short* __restrict__ WqkvT,
                     unsigned short* __restrict__ W1T, unsigned short* __restrict__ W2T,
                     float* __restrict__ bqkv)
{
    const int i0 = blockIdx.x * blockDim.x + threadIdx.x;
    const int stride = gridDim.x * blockDim.x;
    for (int e = i0; e < N_EDGES; e += stride) {
        int src = ei[e];
        int dst = ei[N_EDGES + e];
        int slot = atomicAdd(&deg[src], 1);
        if (slot < MAXD) col[src * MAXD + slot] = dst;
    }
    for (int idx = i0; idx < DIM_IN * DIM_H; idx += stride) {    // W_in[128][256]
        int k = idx >> 8, n = idx & 255;
        WinT[n * DIM_IN + k] = f2bf(W_in[idx]);
    }
    for (int idx = i0; idx < DIM_H * DIM_C; idx += stride) {     // Wq[256][32] -> rows 0..31
        int k = idx >> 5, n = idx & 31;
        WqkvT[n * DIM_H + k] = f2bf(Wq[idx]);
    }
    for (int idx = i0; idx < DIM_H * DIM_C; idx += stride) {     // Wk -> rows 32..63
        int k = idx >> 5, n = idx & 31;
        WqkvT[(DIM_C + n) * DIM_H + k] = f2bf(Wk[idx]);
    }
    for (int idx = i0; idx < DIM_H * DIM_H; idx += stride) {     // Wv[256][256] -> rows 64..319
        int k = idx >> 8, n = idx & 255;
        WqkvT[(2 * DIM_C + n) * DIM_H + k] = f2bf(Wv[idx]);
    }
    for (int idx = i0; idx < DIM_CAT * DIM_H; idx += stride) {   // W1[512][256]
        int k = idx >> 8, n = idx & 255;
        W1T[n * DIM_CAT + k] = f2bf(W1[idx]);
    }
    for (int idx = i0; idx < DIM_H * DIM_OUT; idx += stride) {   // W2[256][64]
        int k = idx >> 6, n = idx & 63;
        W2T[n * DIM_H + k] = f2bf(W2[idx]);
    }
    for (int idx = i0; idx < DIM_QKV; idx += stride)
        bqkv[idx] = (idx < DIM_C) ? bq[idx]
                  : (idx < 2 * DIM_C) ? bk[idx - DIM_C] : bv[idx - 2 * DIM_C];
}

// ---------------- fused GEMM1+GEMM2, BM=32 (313 blocks, ~1.5 blocks/CU) ---------------
// h = x@Win+b computed per 32-row strip, kept in LDS, immediately consumed for
// qkv = h@Wqkv+b. x cast f32->bf16 inline during A-staging.
// LDS: hS 32x264 (16.9K) + As 32x40 (2.5K) + Bs 320x40 (25.6K) = 45.1 KB -> 3 blocks/CU.
__global__ __launch_bounds__(256)
void gemm12(const float* __restrict__ x,
            const unsigned short* __restrict__ WinT, const float* __restrict__ b_in,
            const unsigned short* __restrict__ WqkvT, const float* __restrict__ bqkv,
            unsigned short* __restrict__ cat_bf, float* __restrict__ qk,
            unsigned short* __restrict__ v_tab)
{
    __shared__ short hS[32 * HP];       // 16,896 B
    __shared__ short As[32 * PAD];      //  2,560 B (x tile)
    __shared__ short Bs[320 * PAD];     // 25,600 B (weight tile)
    const int tid   = threadIdx.x;
    const int wave  = tid >> 6;
    const int lane  = tid & 63;
    const int quad  = lane >> 4;
    const int col16 = lane & 15;
    const int sr    = tid >> 2;          // B-staging row 0..63
    const int sc    = (tid & 3) * 8;     // B-staging k-chunk (8 bf16 = 16B)
    const int ar    = tid >> 3;          // A-staging row 0..31
    const int ac    = (tid & 7) * 4;     // A-staging k-chunk (4 f32 = 16B -> 4 bf16)
    const int row0  = blockIdx.x * 32;

    // ---- phase 1: h = x @ WinT^T + b_in  (K=128, N=256; wave owns 64 cols) ----
    floatx4 acc[2][4] = {};
    for (int k0 = 0; k0 < DIM_IN; k0 += 32) {
        {   // x tile 32x32: load f32 coalesced, cast inline
            int gr = row0 + ar;
            float4 a = {};
            if (gr < N_NODES) a = *(const float4*)(x + (size_t)gr * DIM_IN + k0 + ac);
            uint2 o;
            o.x = (uint32_t)f2bf(a.x) | ((uint32_t)f2bf(a.y) << 16);
            o.y = (uint32_t)f2bf(a.z) | ((uint32_t)f2bf(a.w) << 16);
            *(uint2*)(As + ar * PAD + ac) = o;
        }
        #pragma unroll
        for (int p = 0; p < 4; ++p) {   // WinT tile 256x32
            int r = sr + p * 64;
            *(short8*)(Bs + r * PAD + sc) = *(const short8*)(WinT + (size_t)r * DIM_IN + k0 + sc);
        }
        __syncthreads();
        short8 af[2], bfr[4];
        #pragma unroll
        for (int m = 0; m < 2; ++m)
            af[m] = *(const short8*)(As + (m * 16 + col16) * PAD + quad * 8);
        #pragma unroll
        for (int n = 0; n < 4; ++n)
            bfr[n] = *(const short8*)(Bs + (wave * 64 + n * 16 + col16) * PAD + quad * 8);
        #pragma unroll
        for (int m = 0; m < 2; ++m)
            #pragma unroll
            for (int n = 0; n < 4; ++n)
                acc[m][n] = MFMA16(af[m], bfr[n], acc[m][n], 0, 0, 0);
        __syncthreads();
    }
    // epilogue 1: bias -> bf16 -> hS (LDS) + cat_bf[:, 0:256] (global, for w1w2)
    #pragma unroll
    for (int m = 0; m < 2; ++m)
        #pragma unroll
        for (int n = 0; n < 4; ++n) {
            int gc = wave * 64 + n * 16 + col16;
            float bia = b_in[gc];
            #pragma unroll
            for (int r = 0; r < 4; ++r) {
                int lr = m * 16 + quad * 4 + r;
                unsigned short hv = f2bf(acc[m][n][r] + bia);
                hS[lr * HP + gc] = (short)hv;
                if (row0 + lr < N_NODES) cat_bf[(size_t)(row0 + lr) * DIM_CAT + gc] = hv;
            }
        }
    __syncthreads();

    // ---- phase 2: qkv = h @ WqkvT^T + bqkv  (K=256, N=320; wave owns 80 cols) ----
    floatx4 acc2[2][5] = {};
    for (int k0 = 0; k0 < DIM_H; k0 += 32) {
        #pragma unroll
        for (int p = 0; p < 5; ++p) {   // WqkvT tile 320x32
            int r = sr + p * 64;
            *(short8*)(Bs + r * PAD + sc) = *(const short8*)(WqkvT + (size_t)r * DIM_H + k0 + sc);
        }
        __syncthreads();
        short8 af[2], bfr[5];
        #pragma unroll
        for (int m = 0; m < 2; ++m)
            af[m] = *(const short8*)(hS + (m * 16 + col16) * HP + k0 + quad * 8);
        #pragma unroll
        for (int n = 0; n < 5; ++n)
            bfr[n] = *(const short8*)(Bs + (wave * 80 + n * 16 + col16) * PAD + quad * 8);
        #pragma unroll
        for (int m = 0; m < 2; ++m)
            #pragma unroll
            for (int n = 0; n < 5; ++n)
                acc2[m][n] = MFMA16(af[m], bfr[n], acc2[m][n], 0, 0, 0);
        __syncthreads();
    }
    // epilogue 2: split -> qk fp32 [N][64], v fp8/bf16 [N][256]
    #pragma unroll
    for (int m = 0; m < 2; ++m)
        #pragma unroll
        for (int n = 0; n < 5; ++n) {
            int gc = wave * 80 + n * 16 + col16;
            float bia = bqkv[gc];
            #pragma unroll
            for (int r = 0; r < 4; ++r) {
                int gr = row0 + m * 16 + quad * 4 + r;
                if (gr >= N_NODES) continue;
                float v = acc2[m][n][r] + bia;
                if (gc < DIM_QK) {
                    qk[(size_t)gr * DIM_QK + gc] = v;
                } else {
#if V_FP8
                    int pk = __builtin_amdgcn_cvt_pk_fp8_f32(v * VSCALE, 0.f, 0, false);
                    ((unsigned char*)v_tab)[(size_t)gr * DIM_H + (gc - DIM_QK)] =
                        (unsigned char)(pk & 0xff);
#else
                    v_tab[(size_t)gr * DIM_H + (gc - DIM_QK)] = f2bf(v);
#endif
                }
            }
        }
}

// ---------------- fused per-row attention: dedup + softmax + weighted v-gather --------
// One wave per row, 4 rows per block (2500 blocks). Proven structure.
__global__ __launch_bounds__(256)
void attn_row(const float* __restrict__ qk, const unsigned short* __restrict__ v_tab,
              const int* __restrict__ deg, const int* __restrict__ col,
              unsigned short* __restrict__ cat_bf) {
    __shared__ int   dstS[4][MAXD];
    __shared__ float wS[4][MAXD];
    __shared__ float qS[4][DIM_C];
    const int wave = threadIdx.x >> 6;
    const int lane = threadIdx.x & 63;
    const int row = blockIdx.x * 4 + wave;   // grid is exactly N_NODES/4
    int d = deg[row];
    if (d > MAXD) d = MAXD;
    const int* crow = col + (size_t)row * MAXD;

    for (int p = lane; p < d; p += 64) dstS[wave][p] = crow[p];
    if (lane < DIM_C) qS[wave][lane] = qk[(size_t)row * DIM_QK + lane];
    __syncthreads();

    float mysum = 0.f;
    if (d <= 64) {
        int mydst = (lane < d) ? dstS[wave][lane] : -1;
        bool dup = false;
        for (int k2 = 0; k2 < d - 1; ++k2) {            // dynamic bound (~31 iters avg)
            int other = __shfl(mydst, k2, 64);
            dup = dup || (k2 < lane && other == mydst);
        }
        float w = 0.f;
        if (lane < d && !dup) {
            const float4* kp = (const float4*)(qk + (size_t)mydst * DIM_QK + DIM_C);
            float s = 0.f;
            #pragma unroll
            for (int i = 0; i < DIM_C / 4; ++i) {
                float4 b = kp[i];
                s += qS[wave][4 * i + 0] * b.x + qS[wave][4 * i + 1] * b.y
                   + qS[wave][4 * i + 2] * b.z + qS[wave][4 * i + 3] * b.w;
            }
            w = expf(s * SCALE);
        }
        wS[wave][lane] = w;
        mysum = w;
    } else {
        for (int p = lane; p < d; p += 64) {
            int mydst = dstS[wave][p];
            bool dup = false;
            for (int j = 0; j < p; ++j) dup = dup || (dstS[wave][j] == mydst);
            float w = 0.f;
            if (!dup) {
                const float4* kp = (const float4*)(qk + (size_t)mydst * DIM_QK + DIM_C);
                float s = 0.f;
                #pragma unroll
                for (int i = 0; i < DIM_C / 4; ++i) {
                    float4 b = kp[i];
                    s += qS[wave][4 * i + 0] * b.x + qS[wave][4 * i + 1] * b.y
                       + qS[wave][4 * i + 2] * b.z + qS[wave][4 * i + 3] * b.w;
                }
                w = expf(s * SCALE);
            }
            wS[wave][p] = w;
            mysum += w;
        }
    }
    #pragma unroll
    for (int off = 32; off; off >>= 1) mysum += __shfl_down(mysum, off, 64);
    float total = __shfl(mysum, 0, 64);
#if V_FP8
    float inv = (d > 0 && total > 0.f) ? 1.0f / (total * VSCALE) : 0.f;
#else
    float inv = (d > 0 && total > 0.f) ? 1.0f / total : 0.f;
#endif
    __syncthreads();

    float4 acc = make_float4(0.f, 0.f, 0.f, 0.f);
#if V_FP8
    const uint32_t* vb = (const uint32_t*)v_tab;     // fp8 row = 64 dwords
#else
    const uint2* vb = (const uint2*)v_tab;           // bf16 row = 64 uint2
#endif
    for (int p0 = 0; p0 < d; p0 += 16) {
        int j[16]; float w[16];
        #pragma unroll
        for (int t = 0; t < 16; ++t) {
            int idx = p0 + t;
            bool in = idx < d;
            j[t] = in ? dstS[wave][idx] : 0;        // pad: row 0 (L2-hot), weight 0
            w[t] = in ? wS[wave][idx] : 0.f;
        }
#if V_FP8
        uint32_t r[16];
        #pragma unroll
        for (int t = 0; t < 16; ++t) r[t] = vb[(size_t)j[t] * 64 + lane];
        #pragma unroll
        for (int t = 0; t < 16; ++t) {
            floatx2 lo = __builtin_amdgcn_cvt_pk_f32_fp8(r[t], false);
            floatx2 hi = __builtin_amdgcn_cvt_pk_f32_fp8(r[t], true);
            acc.x += w[t] * lo.x; acc.y += w[t] * lo.y;
            acc.z += w[t] * hi.x; acc.w += w[t] * hi.y;
        }
#else
        uint2 r[16];
        #pragma unroll
        for (int t = 0; t < 16; ++t) r[t] = vb[(size_t)j[t] * 64 + lane];
        #pragma unroll
        for (int t = 0; t < 16; ++t) {
            acc.x += w[t] * bf2f_lo(r[t].x);
            acc.y += w[t] * bf2f_hi(r[t].x);
            acc.z += w[t] * bf2f_lo(r[t].y);
            acc.w += w[t] * bf2f_hi(r[t].y);
        }
#endif
    }
    acc.x *= inv; acc.y *= inv; acc.z *= inv; acc.w *= inv;
    uint2 o;
    o.x = (uint32_t)f2bf(acc.x) | ((uint32_t)f2bf(acc.y) << 16);
    o.y = (uint32_t)f2bf(acc.z) | ((uint32_t)f2bf(acc.w) << 16);
    *(uint2*)(cat_bf + (size_t)row * DIM_CAT + DIM_H + lane * 4) = o;
}

// ---------------- fused W1(relu) + W2 GEMM, BM=32 (313 blocks) ------------------------
// Phase A: 4 waves each 32x64 (acc 2x4), z -> LDS (Ts aliases Bs).
// Phase B: z @ W2T^T, each wave 32x16 (acc 2x1), K=256. Verified in round-2 megakernel.
__global__ __launch_bounds__(256)
void gemm_w1w2(const unsigned short* __restrict__ cat, const unsigned short* __restrict__ W1T,
               const float* __restrict__ b1, const unsigned short* __restrict__ W2T,
               const float* __restrict__ b2, float* __restrict__ out, int M)
{
    constexpr int TP = 260;   // Ts row stride (bf16)
    __shared__ short As[32 * PAD];                 //  2,560 B
    __shared__ short BsTs[256 * PAD];              // 20,480 B: Bs; Ts (32*260*2=16,640) aliases
    short* Bs = BsTs;
    short* Ts = BsTs;
    const int tid   = threadIdx.x;
    const int wave  = tid >> 6;
    const int lane  = tid & 63;
    const int quad  = lane >> 4;
    const int col16 = lane & 15;
    const int row0  = blockIdx.x * 32;

    const int sr = tid >> 2;          // 0..63
    const int sc = (tid & 3) * 8;     // 16B k-chunk

    // ---- phase A: z = relu(cat @ W1T^T + b1), 32 rows x 256 cols ----
    floatx4 acc[2][4] = {};
    for (int k0 = 0; k0 < DIM_CAT; k0 += 32) {
        if (sr < 32) {   // A tile: 32 rows x 32 k
            int gr = row0 + sr;
            short8 v = {};
            if (gr < M) v = *(const short8*)(cat + (size_t)gr * DIM_CAT + k0 + sc);
            *(short8*)(As + sr * PAD + sc) = v;
        }
        #pragma unroll
        for (int p = 0; p < 4; ++p) {  // B tile: 256 n-rows x 32 k
            int r = sr + p * 64;
            *(short8*)(Bs + r * PAD + sc) = *(const short8*)(W1T + (size_t)r * DIM_CAT + k0 + sc);
        }
        __syncthreads();
        short8 af[2], bfr[4];
        #pragma unroll
        for (int m = 0; m < 2; ++m)
            af[m] = *(const short8*)(As + (m * 16 + col16) * PAD + quad * 8);
        #pragma unroll
        for (int n = 0; n < 4; ++n)
            bfr[n] = *(const short8*)(Bs + (wave * 64 + n * 16 + col16) * PAD + quad * 8);
        #pragma unroll
        for (int m = 0; m < 2; ++m)
            #pragma unroll
            for (int n = 0; n < 4; ++n)
                acc[m][n] = MFMA16(af[m], bfr[n], acc[m][n], 0, 0, 0);
        __syncthreads();   // Bs reads done before next staging / Ts overwrite
    }

    // epilogue A: bias + relu -> bf16 z tile in Ts (aliases Bs; safe after final barrier)
    #pragma unroll
    for (int m = 0; m < 2; ++m)
        #pragma unroll
        for (int n = 0; n < 4; ++n) {
            int gc = wave * 64 + n * 16 + col16;
            float bia = b1[gc];
            #pragma unroll
            for (int r = 0; r < 4; ++r) {
                int lr = m * 16 + quad * 4 + r;
                Ts[lr * TP + gc] = (short)f2bf(fmaxf(acc[m][n][r] + bia, 0.f));
            }
        }
    __syncthreads();

    // ---- phase B: out = z @ W2T^T + b2, K=256; wave owns cols [wave*16, wave*16+16) ----
    floatx4 acc2[2] = {};
    for (int k0 = 0; k0 < DIM_H; k0 += 32) {
        short8 b = *(const short8*)(W2T + (size_t)(wave * 16 + col16) * DIM_H + k0 + quad * 8);
        #pragma unroll
        for (int m = 0; m < 2; ++m) {
            short8 a = *(const short8*)(Ts + (m * 16 + col16) * TP + k0 + quad * 8);
            acc2[m] = MFMA16(a, b, acc2[m], 0, 0, 0);
        }
    }
    #pragma unroll
    for (int m = 0; m < 2; ++m) {
        int gc = wave * 16 + col16;
        float bia = b2[gc];
        #pragma unroll
        for (int r = 0; r < 4; ++r) {
            int gr = row0 + m * 16 + quad * 4 + r;
            if (gr < M) out[(size_t)gr * DIM_OUT + gc] = acc2[m][r] + bia;
        }
    }
}

// ---------------- launcher ----------------
extern "C" void kernel_launch(void* const* d_in, const int* in_sizes, int n_in,
                              void* d_out, int out_size, void* d_ws, size_t ws_size,
                              hipStream_t stream) {
    (void)in_sizes; (void)n_in; (void)out_size; (void)ws_size;
    const float* x    = (const float*)d_in[0];
    const int*   ei   = (const int*)d_in[1];
    const float* W_in = (const float*)d_in[2];
    const float* b_in = (const float*)d_in[3];
    const float* Wq   = (const float*)d_in[4];
    const float* bq   = (const float*)d_in[5];
    const float* Wk   = (const float*)d_in[6];
    const float* bk   = (const float*)d_in[7];
    const float* Wv   = (const float*)d_in[8];
    const float* bv   = (const float*)d_in[9];
    const float* W1   = (const float*)d_in[10];
    const float* b1   = (const float*)d_in[11];
    const float* W2   = (const float*)d_in[12];
    const float* b2   = (const float*)d_in[13];
    float* out = (float*)d_out;

    uint32_t* ws      = (uint32_t*)d_ws;
    int*      deg     = (int*)(ws + OFF_DEG);
    int*      col     = (int*)(ws + OFF_COL);
    float*    qk      = (float*)(ws + OFF_QK);
    float*    bqkv    = (float*)(ws + OFF_BQKV);
    unsigned short* v_tab  = (unsigned short*)(ws + OFF_VT);
    unsigned short* cat_bf = (unsigned short*)(ws + OFF_CATBF);
    unsigned short* WinT   = (unsigned short*)(ws + OFF_WINT);
    unsigned short* WqkvT  = (unsigned short*)(ws + OFF_WQKVT);
    unsigned short* W1T    = (unsigned short*)(ws + OFF_W1T);
    unsigned short* W2T    = (unsigned short*)(ws + OFF_W2T);

    // 0) zero deg (40 KB) + fused prep (edges + weight transposes + bias concat)
    hipMemsetAsync(deg, 0, N_NODES * sizeof(int), stream);
    prep<<<640, 256, 0, stream>>>(ei, W_in, Wq, Wk, Wv, bq, bk, bv, W1, W2,
                                  deg, col, WinT, WqkvT, W1T, W2T, bqkv);
    // 1+2) fused h-GEMM + qkv-GEMM, 32-row strips (313 blocks)
    gemm12<<<(N_NODES + 31) / 32, 256, 0, stream>>>(
        x, WinT, b_in, WqkvT, bqkv, cat_bf, qk, v_tab);
    // 3) fused sparse attention (dedup + softmax + v-gather)
    attn_row<<<N_NODES / 4, 256, 0, stream>>>(qk, v_tab, deg, col, cat_bf);
    // 4+5) out = relu(cat@W1+b1)@W2 + b2, 32-row strips (313 blocks), z kept on-CU
    gemm_w1w2<<<(N_NODES + 31) / 32, 256, 0, stream>>>(
        cat_bf, W1T, b1, W2T, b2, out, N_NODES);
}

// Round 6
// 166.670 us; speedup vs baseline: 4.2780x; 1.0129x over previous
//
#include <hip/hip_runtime.h>
#include <stdint.h>
#include <stddef.h>

// Problem constants (fixed by the reference).
constexpr int N_NODES = 10000;
constexpr int N_EDGES = 320000;
constexpr int DIM_IN  = 128;
constexpr int DIM_H   = 256;
constexpr int DIM_C   = 32;
constexpr int DIM_OUT = 64;
constexpr int DIM_QKV = DIM_C + DIM_C + DIM_H;  // 320 : [q|k|v]
constexpr int DIM_QK  = 2 * DIM_C;              // 64  : [q|k] compact fp32
constexpr int DIM_CAT = 2 * DIM_H;              // 512 : [h|comm]
constexpr float SCALE = 0.17677669529663687f;   // 1/sqrt(32)
constexpr int MAXD = 192;   // bucket capacity; Binomial(320k,1e-4) max ~66 (28 sigma margin)
constexpr float VSCALE = 64.0f;                 // fp8 v pre-scale (|v|max ~0.5 -> ~32 << 448)
constexpr int PAD  = 40;    // 32-k LDS row stride (bf16): 80B rows, 16B-aligned
constexpr int PAD2 = 72;    // 64-k LDS row stride (bf16): 144B rows, 16B-aligned (72=8*9)
constexpr int HP   = 264;   // h-tile LDS row stride: 528B rows, 16B-aligned

#if __has_builtin(__builtin_amdgcn_cvt_pk_f32_fp8) && __has_builtin(__builtin_amdgcn_cvt_pk_fp8_f32)
#define V_FP8 1
#else
#define V_FP8 0   // fallback: bf16 v
#endif

// ---------------- workspace layout (4-byte words) ----------------
constexpr size_t alignw(size_t w) { return (w + 15) & ~size_t(15); }
constexpr size_t OFF_DEG   = 0;
constexpr size_t OFF_COL   = alignw(OFF_DEG + N_NODES);                  // [N][MAXD] bucket
constexpr size_t OFF_QK    = alignw(OFF_COL + (size_t)N_NODES * MAXD);   // fp32 [N][64]
constexpr size_t OFF_VT    = alignw(OFF_QK + (size_t)N_NODES * DIM_QK);         // [N][256] fp8/bf16
constexpr size_t OFF_CATBF = alignw(OFF_VT + (size_t)N_NODES * DIM_H / 2);      // [N][512]
constexpr size_t OFF_WINT  = alignw(OFF_CATBF + (size_t)N_NODES * DIM_CAT / 2); // [256][128]
constexpr size_t OFF_WQKVT = alignw(OFF_WINT + (size_t)DIM_H * DIM_IN / 2);     // [320][256]
constexpr size_t OFF_W1T   = alignw(OFF_WQKVT + (size_t)DIM_QKV * DIM_H / 2);   // [256][512]
constexpr size_t OFF_W2T   = alignw(OFF_W1T + (size_t)DIM_H * DIM_CAT / 2);     // [64][256]

typedef __attribute__((ext_vector_type(8))) short short8;
typedef __attribute__((ext_vector_type(4))) float floatx4;
typedef __attribute__((ext_vector_type(2))) float floatx2;

#define MFMA16 __builtin_amdgcn_mfma_f32_16x16x32_bf16

__device__ inline unsigned short f2bf(float f) {
    uint32_t u = __builtin_bit_cast(uint32_t, f);
    uint32_t r = (u + 0x7fffu + ((u >> 16) & 1u)) >> 16;   // RNE
    return (unsigned short)r;
}
__device__ inline float bf2f_lo(uint32_t u) { return __builtin_bit_cast(float, u << 16); }
__device__ inline float bf2f_hi(uint32_t u) { return __builtin_bit_cast(float, u & 0xffff0000u); }

// ---------------- prep_w: ONLY what gemm12 needs (critical path minimized) ------------
// deg zero (race-free: edge scatter moved to gemm12, next kernel) + WinT/WqkvT transpose.
__global__ void prep_w(const float* __restrict__ W_in,
                       const float* __restrict__ Wq, const float* __restrict__ Wk,
                       const float* __restrict__ Wv,
                       int* __restrict__ deg,
                       unsigned short* __restrict__ WinT, unsigned short* __restrict__ WqkvT)
{
    const int i0 = blockIdx.x * blockDim.x + threadIdx.x;
    const int stride = gridDim.x * blockDim.x;
    for (int i = i0; i < N_NODES; i += stride) deg[i] = 0;
    for (int idx = i0; idx < DIM_IN * DIM_H; idx += stride) {    // W_in[128][256]
        int k = idx >> 8, n = idx & 255;
        WinT[n * DIM_IN + k] = f2bf(W_in[idx]);
    }
    for (int idx = i0; idx < DIM_H * DIM_C; idx += stride) {     // Wq[256][32] -> rows 0..31
        int k = idx >> 5, n = idx & 31;
        WqkvT[n * DIM_H + k] = f2bf(Wq[idx]);
    }
    for (int idx = i0; idx < DIM_H * DIM_C; idx += stride) {     // Wk -> rows 32..63
        int k = idx >> 5, n = idx & 31;
        WqkvT[(DIM_C + n) * DIM_H + k] = f2bf(Wk[idx]);
    }
    for (int idx = i0; idx < DIM_H * DIM_H; idx += stride) {     // Wv[256][256] -> rows 64..319
        int k = idx >> 8, n = idx & 255;
        WqkvT[(2 * DIM_C + n) * DIM_H + k] = f2bf(Wv[idx]);
    }
}

// ---------------- fused GEMM1+GEMM2, BM=32, K-step 64 (313 blocks) --------------------
// Head: edge bucket-scatter slice (hides under GEMM staging).
// Phase 1: h = x@WinT^T + b_in (K=128, 2 k-steps), h -> LDS + cat_bf[:,0:256].
// Phase 2: qkv = h@WqkvT^T + b (K=256, 4 k-steps) -> qk fp32 / v fp8.
// Tail: W1T/W2T transpose (needed 2 kernels later by w1w2).
// LDS 62,976 B: hS 32x264 | phase1 {As1 32x72, Bs1 256x72} overlapped by phase2 Bs2 320x72.
__global__ __launch_bounds__(256)
void gemm12(const float* __restrict__ x, const int* __restrict__ ei,
            const unsigned short* __restrict__ WinT, const float* __restrict__ b_in,
            const unsigned short* __restrict__ WqkvT,
            const float* __restrict__ bq, const float* __restrict__ bk,
            const float* __restrict__ bv,
            const float* __restrict__ W1, const float* __restrict__ W2,
            int* __restrict__ deg, int* __restrict__ col,
            unsigned short* __restrict__ cat_bf, float* __restrict__ qk,
            unsigned short* __restrict__ v_tab,
            unsigned short* __restrict__ W1T, unsigned short* __restrict__ W2T)
{
    __shared__ alignas(16) char SMEM[62976];
    short* hS  = (short*)SMEM;                    // 32 x 264 = 16,896 B
    short* As1 = (short*)(SMEM + 16896);          // 32 x 72  =  4,608 B (phase 1)
    short* Bs1 = (short*)(SMEM + 21504);          // 256 x 72 = 36,864 B (phase 1)
    short* Bs2 = (short*)(SMEM + 16896);          // 320 x 72 = 46,080 B (phase 2, overlaps)
    const int tid   = threadIdx.x;
    const int bid   = blockIdx.x;
    const int wave  = tid >> 6;
    const int lane  = tid & 63;
    const int quad  = lane >> 4;
    const int col16 = lane & 15;
    const int sr    = tid >> 3;          // staging row 0..31
    const int sc    = (tid & 7) * 8;     // staging k-chunk (8 bf16 = 16B), 0..56
    const int row0  = bid * 32;

    // ---- head: edge bucket-scatter slice, 4-deep unrolled (loads all in flight) ----
    {
        const int stride = gridDim.x * 256;              // 80,128
        const int i0 = bid * 256 + tid;
        int s4[4], d4[4]; bool ok[4];
        #pragma unroll
        for (int t = 0; t < 4; ++t) {
            int e = i0 + t * stride;
            ok[t] = e < N_EDGES;
            s4[t] = ok[t] ? ei[e] : 0;
            d4[t] = ok[t] ? ei[N_EDGES + e] : 0;
        }
        #pragma unroll
        for (int t = 0; t < 4; ++t)
            if (ok[t]) {
                int slot = atomicAdd(&deg[s4[t]], 1);
                if (slot < MAXD) col[s4[t] * MAXD + slot] = d4[t];
            }
    }

    // ---- phase 1: h = x @ WinT^T + b_in  (K=128, 2 k-steps of 64) ----
    floatx4 acc[2][4] = {};
    for (int k0 = 0; k0 < DIM_IN; k0 += 64) {
        {   // x tile 32x64: f32 coalesced load, inline cast
            int gr = row0 + sr;
            float4 a = {}, b = {};
            if (gr < N_NODES) {
                const float4* xp = (const float4*)(x + (size_t)gr * DIM_IN + k0 + sc);
                a = xp[0]; b = xp[1];
            }
            uint4 o;
            o.x = (uint32_t)f2bf(a.x) | ((uint32_t)f2bf(a.y) << 16);
            o.y = (uint32_t)f2bf(a.z) | ((uint32_t)f2bf(a.w) << 16);
            o.z = (uint32_t)f2bf(b.x) | ((uint32_t)f2bf(b.y) << 16);
            o.w = (uint32_t)f2bf(b.z) | ((uint32_t)f2bf(b.w) << 16);
            *(uint4*)(As1 + sr * PAD2 + sc) = o;
        }
        #pragma unroll
        for (int p = 0; p < 8; ++p) {   // WinT tile 256x64
            int r = sr + p * 32;
            *(short8*)(Bs1 + r * PAD2 + sc) =
                *(const short8*)(WinT + (size_t)r * DIM_IN + k0 + sc);
        }
        __syncthreads();
        short8 af[2][2], bfr[4][2];
        #pragma unroll
        for (int m = 0; m < 2; ++m)
            #pragma unroll
            for (int kh = 0; kh < 2; ++kh)
                af[m][kh] = *(const short8*)(As1 + (m * 16 + col16) * PAD2 + kh * 32 + quad * 8);
        #pragma unroll
        for (int n = 0; n < 4; ++n)
            #pragma unroll
            for (int kh = 0; kh < 2; ++kh)
                bfr[n][kh] = *(const short8*)(Bs1 + (wave * 64 + n * 16 + col16) * PAD2 + kh * 32 + quad * 8);
        #pragma unroll
        for (int m = 0; m < 2; ++m)
            #pragma unroll
            for (int n = 0; n < 4; ++n)
                #pragma unroll
                for (int kh = 0; kh < 2; ++kh)
                    acc[m][n] = MFMA16(af[m][kh], bfr[n][kh], acc[m][n], 0, 0, 0);
        __syncthreads();
    }
    // epilogue 1: bias -> bf16 -> hS (LDS) + cat_bf[:, 0:256] (global, for w1w2)
    #pragma unroll
    for (int m = 0; m < 2; ++m)
        #pragma unroll
        for (int n = 0; n < 4; ++n) {
            int gc = wave * 64 + n * 16 + col16;
            float bia = b_in[gc];
            #pragma unroll
            for (int r = 0; r < 4; ++r) {
                int lr = m * 16 + quad * 4 + r;
                unsigned short hv = f2bf(acc[m][n][r] + bia);
                hS[lr * HP + gc] = (short)hv;
                if (row0 + lr < N_NODES) cat_bf[(size_t)(row0 + lr) * DIM_CAT + gc] = hv;
            }
        }
    __syncthreads();

    // ---- phase 2: qkv = h @ WqkvT^T + bias  (K=256, 4 k-steps of 64) ----
    floatx4 acc2[2][5] = {};
    for (int k0 = 0; k0 < DIM_H; k0 += 64) {
        #pragma unroll
        for (int p = 0; p < 10; ++p) {  // WqkvT tile 320x64
            int r = sr + p * 32;
            *(short8*)(Bs2 + r * PAD2 + sc) =
                *(const short8*)(WqkvT + (size_t)r * DIM_H + k0 + sc);
        }
        __syncthreads();
        short8 af[2][2], bfr[5][2];
        #pragma unroll
        for (int m = 0; m < 2; ++m)
            #pragma unroll
            for (int kh = 0; kh < 2; ++kh)
                af[m][kh] = *(const short8*)(hS + (m * 16 + col16) * HP + k0 + kh * 32 + quad * 8);
        #pragma unroll
        for (int n = 0; n < 5; ++n)
            #pragma unroll
            for (int kh = 0; kh < 2; ++kh)
                bfr[n][kh] = *(const short8*)(Bs2 + (wave * 80 + n * 16 + col16) * PAD2 + kh * 32 + quad * 8);
        #pragma unroll
        for (int m = 0; m < 2; ++m)
            #pragma unroll
            for (int n = 0; n < 5; ++n)
                #pragma unroll
                for (int kh = 0; kh < 2; ++kh)
                    acc2[m][n] = MFMA16(af[m][kh], bfr[n][kh], acc2[m][n], 0, 0, 0);
        __syncthreads();
    }
    // epilogue 2: split -> qk fp32 [N][64], v fp8/bf16 [N][256]; bias read direct
    #pragma unroll
    for (int m = 0; m < 2; ++m)
        #pragma unroll
        for (int n = 0; n < 5; ++n) {
            int gc = wave * 80 + n * 16 + col16;
            float bia = (gc < DIM_C) ? bq[gc] : (gc < DIM_QK) ? bk[gc - DIM_C] : bv[gc - DIM_QK];
            #pragma unroll
            for (int r = 0; r < 4; ++r) {
                int gr = row0 + m * 16 + quad * 4 + r;
                if (gr >= N_NODES) continue;
                float v = acc2[m][n][r] + bia;
                if (gc < DIM_QK) {
                    qk[(size_t)gr * DIM_QK + gc] = v;
                } else {
#if V_FP8
                    int pk = __builtin_amdgcn_cvt_pk_fp8_f32(v * VSCALE, 0.f, 0, false);
                    ((unsigned char*)v_tab)[(size_t)gr * DIM_H + (gc - DIM_QK)] =
                        (unsigned char)(pk & 0xff);
#else
                    v_tab[(size_t)gr * DIM_H + (gc - DIM_QK)] = f2bf(v);
#endif
                }
            }
        }

    // ---- tail: W1T/W2T transpose (consumed by w1w2, 2 kernels later) ----
    {
        const int stride = gridDim.x * 256;
        const int i0 = bid * 256 + tid;
        for (int idx = i0; idx < DIM_CAT * DIM_H; idx += stride) {   // W1[512][256]
            int k = idx >> 8, n = idx & 255;
            W1T[n * DIM_CAT + k] = f2bf(W1[idx]);
        }
        for (int idx = i0; idx < DIM_H * DIM_OUT; idx += stride) {   // W2[256][64]
            int k = idx >> 6, n = idx & 63;
            W2T[n * DIM_H + k] = f2bf(W2[idx]);
        }
    }
}

// ---------------- fused per-row attention: dedup + softmax + weighted v-gather --------
// One wave per row, 4 rows per block (2500 blocks). Proven structure, unchanged.
__global__ __launch_bounds__(256)
void attn_row(const float* __restrict__ qk, const unsigned short* __restrict__ v_tab,
              const int* __restrict__ deg, const int* __restrict__ col,
              unsigned short* __restrict__ cat_bf) {
    __shared__ int   dstS[4][MAXD];
    __shared__ float wS[4][MAXD];
    __shared__ float qS[4][DIM_C];
    const int wave = threadIdx.x >> 6;
    const int lane = threadIdx.x & 63;
    const int row = blockIdx.x * 4 + wave;   // grid is exactly N_NODES/4
    int d = deg[row];
    if (d > MAXD) d = MAXD;
    const int* crow = col + (size_t)row * MAXD;

    for (int p = lane; p < d; p += 64) dstS[wave][p] = crow[p];
    if (lane < DIM_C) qS[wave][lane] = qk[(size_t)row * DIM_QK + lane];
    __syncthreads();

    float mysum = 0.f;
    if (d <= 64) {
        int mydst = (lane < d) ? dstS[wave][lane] : -1;
        bool dup = false;
        for (int k2 = 0; k2 < d - 1; ++k2) {            // dynamic bound (~31 iters avg)
            int other = __shfl(mydst, k2, 64);
            dup = dup || (k2 < lane && other == mydst);
        }
        float w = 0.f;
        if (lane < d && !dup) {
            const float4* kp = (const float4*)(qk + (size_t)mydst * DIM_QK + DIM_C);
            float s = 0.f;
            #pragma unroll
            for (int i = 0; i < DIM_C / 4; ++i) {
                float4 b = kp[i];
                s += qS[wave][4 * i + 0] * b.x + qS[wave][4 * i + 1] * b.y
                   + qS[wave][4 * i + 2] * b.z + qS[wave][4 * i + 3] * b.w;
            }
            w = expf(s * SCALE);
        }
        wS[wave][lane] = w;
        mysum = w;
    } else {
        for (int p = lane; p < d; p += 64) {
            int mydst = dstS[wave][p];
            bool dup = false;
            for (int j = 0; j < p; ++j) dup = dup || (dstS[wave][j] == mydst);
            float w = 0.f;
            if (!dup) {
                const float4* kp = (const float4*)(qk + (size_t)mydst * DIM_QK + DIM_C);
                float s = 0.f;
                #pragma unroll
                for (int i = 0; i < DIM_C / 4; ++i) {
                    float4 b = kp[i];
                    s += qS[wave][4 * i + 0] * b.x + qS[wave][4 * i + 1] * b.y
                       + qS[wave][4 * i + 2] * b.z + qS[wave][4 * i + 3] * b.w;
                }
                w = expf(s * SCALE);
            }
            wS[wave][p] = w;
            mysum += w;
        }
    }
    #pragma unroll
    for (int off = 32; off; off >>= 1) mysum += __shfl_down(mysum, off, 64);
    float total = __shfl(mysum, 0, 64);
#if V_FP8
    float inv = (d > 0 && total > 0.f) ? 1.0f / (total * VSCALE) : 0.f;
#else
    float inv = (d > 0 && total > 0.f) ? 1.0f / total : 0.f;
#endif
    __syncthreads();

    float4 acc = make_float4(0.f, 0.f, 0.f, 0.f);
#if V_FP8
    const uint32_t* vb = (const uint32_t*)v_tab;     // fp8 row = 64 dwords
#else
    const uint2* vb = (const uint2*)v_tab;           // bf16 row = 64 uint2
#endif
    for (int p0 = 0; p0 < d; p0 += 16) {
        int j[16]; float w[16];
        #pragma unroll
        for (int t = 0; t < 16; ++t) {
            int idx = p0 + t;
            bool in = idx < d;
            j[t] = in ? dstS[wave][idx] : 0;        // pad: row 0 (L2-hot), weight 0
            w[t] = in ? wS[wave][idx] : 0.f;
        }
#if V_FP8
        uint32_t r[16];
        #pragma unroll
        for (int t = 0; t < 16; ++t) r[t] = vb[(size_t)j[t] * 64 + lane];
        #pragma unroll
        for (int t = 0; t < 16; ++t) {
            floatx2 lo = __builtin_amdgcn_cvt_pk_f32_fp8(r[t], false);
            floatx2 hi = __builtin_amdgcn_cvt_pk_f32_fp8(r[t], true);
            acc.x += w[t] * lo.x; acc.y += w[t] * lo.y;
            acc.z += w[t] * hi.x; acc.w += w[t] * hi.y;
        }
#else
        uint2 r[16];
        #pragma unroll
        for (int t = 0; t < 16; ++t) r[t] = vb[(size_t)j[t] * 64 + lane];
        #pragma unroll
        for (int t = 0; t < 16; ++t) {
            acc.x += w[t] * bf2f_lo(r[t].x);
            acc.y += w[t] * bf2f_hi(r[t].x);
            acc.z += w[t] * bf2f_lo(r[t].y);
            acc.w += w[t] * bf2f_hi(r[t].y);
        }
#endif
    }
    acc.x *= inv; acc.y *= inv; acc.z *= inv; acc.w *= inv;
    uint2 o;
    o.x = (uint32_t)f2bf(acc.x) | ((uint32_t)f2bf(acc.y) << 16);
    o.y = (uint32_t)f2bf(acc.z) | ((uint32_t)f2bf(acc.w) << 16);
    *(uint2*)(cat_bf + (size_t)row * DIM_CAT + DIM_H + lane * 4) = o;
}

// ---------------- fused W1(relu) + W2 GEMM, BM=32, K-step 64 (313 blocks) -------------
// Phase A: 8 k-steps of 64, z -> LDS (Ts aliases Bs). Phase B: z @ W2T^T, K=256.
__global__ __launch_bounds__(256)
void gemm_w1w2(const unsigned short* __restrict__ cat, const unsigned short* __restrict__ W1T,
               const float* __restrict__ b1, const unsigned short* __restrict__ W2T,
               const float* __restrict__ b2, float* __restrict__ out, int M)
{
    constexpr int TP = 260;   // Ts row stride (bf16)
    __shared__ short As[32 * PAD2];                //  4,608 B
    __shared__ short BsTs[256 * PAD2];             // 36,864 B: Bs; Ts (32*260*2=16,640) aliases
    short* Bs = BsTs;
    short* Ts = BsTs;
    const int tid   = threadIdx.x;
    const int wave  = tid >> 6;
    const int lane  = tid & 63;
    const int quad  = lane >> 4;
    const int col16 = lane & 15;
    const int row0  = blockIdx.x * 32;

    const int sr = tid >> 3;          // 0..31
    const int sc = (tid & 7) * 8;     // 16B k-chunk, 0..56

    // ---- phase A: z = relu(cat @ W1T^T + b1), 32 rows x 256 cols, K=512 (8 steps) ----
    floatx4 acc[2][4] = {};
    for (int k0 = 0; k0 < DIM_CAT; k0 += 64) {
        {   // A tile: 32 rows x 64 k
            int gr = row0 + sr;
            short8 v = {};
            if (gr < M) v = *(const short8*)(cat + (size_t)gr * DIM_CAT + k0 + sc);
            *(short8*)(As + sr * PAD2 + sc) = v;
        }
        #pragma unroll
        for (int p = 0; p < 8; ++p) {  // B tile: 256 n-rows x 64 k
            int r = sr + p * 32;
            *(short8*)(Bs + r * PAD2 + sc) = *(const short8*)(W1T + (size_t)r * DIM_CAT + k0 + sc);
        }
        __syncthreads();
        short8 af[2][2], bfr[4][2];
        #pragma unroll
        for (int m = 0; m < 2; ++m)
            #pragma unroll
            for (int kh = 0; kh < 2; ++kh)
                af[m][kh] = *(const short8*)(As + (m * 16 + col16) * PAD2 + kh * 32 + quad * 8);
        #pragma unroll
        for (int n = 0; n < 4; ++n)
            #pragma unroll
            for (int kh = 0; kh < 2; ++kh)
                bfr[n][kh] = *(const short8*)(Bs + (wave * 64 + n * 16 + col16) * PAD2 + kh * 32 + quad * 8);
        #pragma unroll
        for (int m = 0; m < 2; ++m)
            #pragma unroll
            for (int n = 0; n < 4; ++n)
                #pragma unroll
                for (int kh = 0; kh < 2; ++kh)
                    acc[m][n] = MFMA16(af[m][kh], bfr[n][kh], acc[m][n], 0, 0, 0);
        __syncthreads();   // Bs reads done before next staging / Ts overwrite
    }

    // epilogue A: bias + relu -> bf16 z tile in Ts (aliases Bs; safe after final barrier)
    #pragma unroll
    for (int m = 0; m < 2; ++m)
        #pragma unroll
        for (int n = 0; n < 4; ++n) {
            int gc = wave * 64 + n * 16 + col16;
            float bia = b1[gc];
            #pragma unroll
            for (int r = 0; r < 4; ++r) {
                int lr = m * 16 + quad * 4 + r;
                Ts[lr * TP + gc] = (short)f2bf(fmaxf(acc[m][n][r] + bia, 0.f));
            }
        }
    __syncthreads();

    // ---- phase B: out = z @ W2T^T + b2, K=256; wave owns cols [wave*16, wave*16+16) ----
    floatx4 acc2[2] = {};
    for (int k0 = 0; k0 < DIM_H; k0 += 32) {
        short8 b = *(const short8*)(W2T + (size_t)(wave * 16 + col16) * DIM_H + k0 + quad * 8);
        #pragma unroll
        for (int m = 0; m < 2; ++m) {
            short8 a = *(const short8*)(Ts + (m * 16 + col16) * TP + k0 + quad * 8);
            acc2[m] = MFMA16(a, b, acc2[m], 0, 0, 0);
        }
    }
    #pragma unroll
    for (int m = 0; m < 2; ++m) {
        int gc = wave * 16 + col16;
        float bia = b2[gc];
        #pragma unroll
        for (int r = 0; r < 4; ++r) {
            int gr = row0 + m * 16 + quad * 4 + r;
            if (gr < M) out[(size_t)gr * DIM_OUT + gc] = acc2[m][r] + bia;
        }
    }
}

// ---------------- launcher: 4 dispatches ----------------
extern "C" void kernel_launch(void* const* d_in, const int* in_sizes, int n_in,
                              void* d_out, int out_size, void* d_ws, size_t ws_size,
                              hipStream_t stream) {
    (void)in_sizes; (void)n_in; (void)out_size; (void)ws_size;
    const float* x    = (const float*)d_in[0];
    const int*   ei   = (const int*)d_in[1];
    const float* W_in = (const float*)d_in[2];
    const float* b_in = (const float*)d_in[3];
    const float* Wq   = (const float*)d_in[4];
    const float* bq   = (const float*)d_in[5];
    const float* Wk   = (const float*)d_in[6];
    const float* bk   = (const float*)d_in[7];
    const float* Wv   = (const float*)d_in[8];
    const float* bv   = (const float*)d_in[9];
    const float* W1   = (const float*)d_in[10];
    const float* b1   = (const float*)d_in[11];
    const float* W2   = (const float*)d_in[12];
    const float* b2   = (const float*)d_in[13];
    float* out = (float*)d_out;

    uint32_t* ws      = (uint32_t*)d_ws;
    int*      deg     = (int*)(ws + OFF_DEG);
    int*      col     = (int*)(ws + OFF_COL);
    float*    qk      = (float*)(ws + OFF_QK);
    unsigned short* v_tab  = (unsigned short*)(ws + OFF_VT);
    unsigned short* cat_bf = (unsigned short*)(ws + OFF_CATBF);
    unsigned short* WinT   = (unsigned short*)(ws + OFF_WINT);
    unsigned short* WqkvT  = (unsigned short*)(ws + OFF_WQKVT);
    unsigned short* W1T    = (unsigned short*)(ws + OFF_W1T);
    unsigned short* W2T    = (unsigned short*)(ws + OFF_W2T);

    // 1) minimal blocking prep: deg zero + WinT/WqkvT transpose
    prep_w<<<256, 256, 0, stream>>>(W_in, Wq, Wk, Wv, deg, WinT, WqkvT);
    // 2) fused h-GEMM + qkv-GEMM (+edge scatter head, +W1T/W2T tail), 313 blocks
    gemm12<<<(N_NODES + 31) / 32, 256, 0, stream>>>(
        x, ei, WinT, b_in, WqkvT, bq, bk, bv, W1, W2,
        deg, col, cat_bf, qk, v_tab, W1T, W2T);
    // 3) fused sparse attention (dedup + softmax + v-gather)
    attn_row<<<N_NODES / 4, 256, 0, stream>>>(qk, v_tab, deg, col, cat_bf);
    // 4) out = relu(cat@W1+b1)@W2 + b2, 313 blocks, z kept on-CU
    gemm_w1w2<<<(N_NODES + 31) / 32, 256, 0, stream>>>(
        cat_bf, W1T, b1, W2T, b2, out, N_NODES);
}

// Round 7
// 162.087 us; speedup vs baseline: 4.3990x; 1.0283x over previous
//
#include <hip/hip_runtime.h>
#include <stdint.h>
#include <stddef.h>

// Problem constants (fixed by the reference).
constexpr int N_NODES = 10000;
constexpr int N_EDGES = 320000;
constexpr int DIM_IN  = 128;
constexpr int DIM_H   = 256;
constexpr int DIM_C   = 32;
constexpr int DIM_OUT = 64;
constexpr int DIM_QKV = DIM_C + DIM_C + DIM_H;  // 320 : [q|k|v]
constexpr int DIM_QK  = 2 * DIM_C;              // 64  : [q|k] compact fp32
constexpr int DIM_CAT = 2 * DIM_H;              // 512 : [h|comm]
constexpr float SCALE = 0.17677669529663687f;   // 1/sqrt(32)
constexpr int MAXD = 192;   // bucket capacity; Binomial(320k,1e-4) max ~66 (28 sigma margin)
constexpr float VSCALE = 64.0f;                 // fp8 v pre-scale (|v|max ~0.5 -> ~32 << 448)
constexpr int PAD2 = 72;    // 64-k LDS row stride (bf16): 144B rows, 16B-aligned (72=8*9)
constexpr int HP   = 264;   // h-tile LDS row stride: 528B rows, 16B-aligned

#if __has_builtin(__builtin_amdgcn_cvt_pk_f32_fp8) && __has_builtin(__builtin_amdgcn_cvt_pk_f32_fp8)
#define V_FP8 1
#else
#define V_FP8 0   // fallback: bf16 v
#endif

// ---------------- workspace layout (4-byte words) ----------------
constexpr size_t alignw(size_t w) { return (w + 15) & ~size_t(15); }
constexpr size_t OFF_DEG   = 0;
constexpr size_t OFF_COL   = alignw(OFF_DEG + N_NODES);                  // [N][MAXD] bucket
constexpr size_t OFF_QK    = alignw(OFF_COL + (size_t)N_NODES * MAXD);   // fp32 [N][64]
constexpr size_t OFF_VT    = alignw(OFF_QK + (size_t)N_NODES * DIM_QK);         // [N][256] fp8/bf16
constexpr size_t OFF_CATBF = alignw(OFF_VT + (size_t)N_NODES * DIM_H / 2);      // [N][512]
constexpr size_t OFF_WINT  = alignw(OFF_CATBF + (size_t)N_NODES * DIM_CAT / 2); // [256][128]
constexpr size_t OFF_WQKVT = alignw(OFF_WINT + (size_t)DIM_H * DIM_IN / 2);     // [320][256]
constexpr size_t OFF_W1T   = alignw(OFF_WQKVT + (size_t)DIM_QKV * DIM_H / 2);   // [256][512]
constexpr size_t OFF_W2T   = alignw(OFF_W1T + (size_t)DIM_H * DIM_CAT / 2);     // [64][256]

typedef __attribute__((ext_vector_type(8))) short short8;
typedef __attribute__((ext_vector_type(4))) float floatx4;
typedef __attribute__((ext_vector_type(2))) float floatx2;

#define MFMA16 __builtin_amdgcn_mfma_f32_16x16x32_bf16

__device__ inline unsigned short f2bf(float f) {
    uint32_t u = __builtin_bit_cast(uint32_t, f);
    uint32_t r = (u + 0x7fffu + ((u >> 16) & 1u)) >> 16;   // RNE
    return (unsigned short)r;
}
__device__ inline float bf2f_lo(uint32_t u) { return __builtin_bit_cast(float, u << 16); }
__device__ inline float bf2f_hi(uint32_t u) { return __builtin_bit_cast(float, u & 0xffff0000u); }

// ---------------- prep_w: ONLY what gemm12 needs (critical path minimized) ------------
__global__ void prep_w(const float* __restrict__ W_in,
                       const float* __restrict__ Wq, const float* __restrict__ Wk,
                       const float* __restrict__ Wv,
                       int* __restrict__ deg,
                       unsigned short* __restrict__ WinT, unsigned short* __restrict__ WqkvT)
{
    const int i0 = blockIdx.x * blockDim.x + threadIdx.x;
    const int stride = gridDim.x * blockDim.x;
    for (int i = i0; i < N_NODES; i += stride) deg[i] = 0;
    for (int idx = i0; idx < DIM_IN * DIM_H; idx += stride) {    // W_in[128][256]
        int k = idx >> 8, n = idx & 255;
        WinT[n * DIM_IN + k] = f2bf(W_in[idx]);
    }
    for (int idx = i0; idx < DIM_H * DIM_C; idx += stride) {     // Wq[256][32] -> rows 0..31
        int k = idx >> 5, n = idx & 31;
        WqkvT[n * DIM_H + k] = f2bf(Wq[idx]);
    }
    for (int idx = i0; idx < DIM_H * DIM_C; idx += stride) {     // Wk -> rows 32..63
        int k = idx >> 5, n = idx & 31;
        WqkvT[(DIM_C + n) * DIM_H + k] = f2bf(Wk[idx]);
    }
    for (int idx = i0; idx < DIM_H * DIM_H; idx += stride) {     // Wv[256][256] -> rows 64..319
        int k = idx >> 8, n = idx & 255;
        WqkvT[(2 * DIM_C + n) * DIM_H + k] = f2bf(Wv[idx]);
    }
}

// ---------------- fused GEMM1+GEMM2, BM=32, K-step 64, REG-PREFETCH pipeline ----------
// Every K-tile's global loads are issued under the PREVIOUS tile's MFMA (latency hidden).
// Edge bucket-scatter + W1T/W2T transpose run in the TAIL (off the MFMA critical path).
// LDS 62,976 B (2 blocks/CU): hS 32x264 | phase1 {As1,Bs1} overlapped by phase2 Bs2.
__global__ __launch_bounds__(256)
void gemm12(const float* __restrict__ x, const int* __restrict__ ei,
            const unsigned short* __restrict__ WinT, const float* __restrict__ b_in,
            const unsigned short* __restrict__ WqkvT,
            const float* __restrict__ bq, const float* __restrict__ bk,
            const float* __restrict__ bv,
            const float* __restrict__ W1, const float* __restrict__ W2,
            int* __restrict__ deg, int* __restrict__ col,
            unsigned short* __restrict__ cat_bf, float* __restrict__ qk,
            unsigned short* __restrict__ v_tab,
            unsigned short* __restrict__ W1T, unsigned short* __restrict__ W2T)
{
    __shared__ alignas(16) char SMEM[62976];
    short* hS  = (short*)SMEM;                    // 32 x 264 = 16,896 B
    short* As1 = (short*)(SMEM + 16896);          // 32 x 72  =  4,608 B (phase 1)
    short* Bs1 = (short*)(SMEM + 21504);          // 256 x 72 = 36,864 B (phase 1)
    short* Bs2 = (short*)(SMEM + 16896);          // 320 x 72 = 46,080 B (phase 2, overlaps)
    const int tid   = threadIdx.x;
    const int bid   = blockIdx.x;
    const int wave  = tid >> 6;
    const int lane  = tid & 63;
    const int quad  = lane >> 4;
    const int col16 = lane & 15;
    const int sr    = tid >> 3;          // staging row 0..31
    const int sc    = (tid & 7) * 8;     // staging k-chunk (8 bf16 = 16B), 0..56
    const int row0  = bid * 32;
    const int gr_s  = row0 + sr;

    // ---- phase-1 prologue: issue k0=0 tile loads (only exposed-latency loads) ----
    float4 xa = {}, xb = {};
    if (gr_s < N_NODES) {
        const float4* xp = (const float4*)(x + (size_t)gr_s * DIM_IN + sc);
        xa = xp[0]; xb = xp[1];
    }
    short8 wreg[8];
    #pragma unroll
    for (int p = 0; p < 8; ++p)
        wreg[p] = *(const short8*)(WinT + (size_t)(sr + p * 32) * DIM_IN + sc);

    short8 breg[10];   // phase-2 prefetch registers
    floatx4 acc[2][4] = {};
    #pragma unroll
    for (int k0 = 0; k0 < DIM_IN; k0 += 64) {
        {   // ds_write staged x tile (inline f32->bf16)
            uint4 o;
            o.x = (uint32_t)f2bf(xa.x) | ((uint32_t)f2bf(xa.y) << 16);
            o.y = (uint32_t)f2bf(xa.z) | ((uint32_t)f2bf(xa.w) << 16);
            o.z = (uint32_t)f2bf(xb.x) | ((uint32_t)f2bf(xb.y) << 16);
            o.w = (uint32_t)f2bf(xb.z) | ((uint32_t)f2bf(xb.w) << 16);
            *(uint4*)(As1 + sr * PAD2 + sc) = o;
        }
        #pragma unroll
        for (int p = 0; p < 8; ++p)
            *(short8*)(Bs1 + (sr + p * 32) * PAD2 + sc) = wreg[p];
        // prefetch: next phase-1 tile, or phase-2 tile 0 (hidden under MFMA below)
        if (k0 + 64 < DIM_IN) {
            xa = {}; xb = {};
            if (gr_s < N_NODES) {
                const float4* xp = (const float4*)(x + (size_t)gr_s * DIM_IN + (k0 + 64) + sc);
                xa = xp[0]; xb = xp[1];
            }
            #pragma unroll
            for (int p = 0; p < 8; ++p)
                wreg[p] = *(const short8*)(WinT + (size_t)(sr + p * 32) * DIM_IN + (k0 + 64) + sc);
        } else {
            #pragma unroll
            for (int p = 0; p < 10; ++p)
                breg[p] = *(const short8*)(WqkvT + (size_t)(sr + p * 32) * DIM_H + sc);
        }
        __syncthreads();
        short8 af[2][2], bfr[4][2];
        #pragma unroll
        for (int m = 0; m < 2; ++m)
            #pragma unroll
            for (int kh = 0; kh < 2; ++kh)
                af[m][kh] = *(const short8*)(As1 + (m * 16 + col16) * PAD2 + kh * 32 + quad * 8);
        #pragma unroll
        for (int n = 0; n < 4; ++n)
            #pragma unroll
            for (int kh = 0; kh < 2; ++kh)
                bfr[n][kh] = *(const short8*)(Bs1 + (wave * 64 + n * 16 + col16) * PAD2 + kh * 32 + quad * 8);
        #pragma unroll
        for (int m = 0; m < 2; ++m)
            #pragma unroll
            for (int n = 0; n < 4; ++n)
                #pragma unroll
                for (int kh = 0; kh < 2; ++kh)
                    acc[m][n] = MFMA16(af[m][kh], bfr[n][kh], acc[m][n], 0, 0, 0);
        __syncthreads();
    }
    // epilogue 1: bias -> bf16 -> hS (LDS) + cat_bf[:, 0:256] (global, for w1w2)
    #pragma unroll
    for (int m = 0; m < 2; ++m)
        #pragma unroll
        for (int n = 0; n < 4; ++n) {
            int gc = wave * 64 + n * 16 + col16;
            float bia = b_in[gc];
            #pragma unroll
            for (int r = 0; r < 4; ++r) {
                int lr = m * 16 + quad * 4 + r;
                unsigned short hv = f2bf(acc[m][n][r] + bia);
                hS[lr * HP + gc] = (short)hv;
                if (row0 + lr < N_NODES) cat_bf[(size_t)(row0 + lr) * DIM_CAT + gc] = hv;
            }
        }
    __syncthreads();

    // ---- phase 2: qkv = h @ WqkvT^T + bias  (K=256, 4 k-steps of 64, prefetched) ----
    floatx4 acc2[2][5] = {};
    #pragma unroll
    for (int k0 = 0; k0 < DIM_H; k0 += 64) {
        #pragma unroll
        for (int p = 0; p < 10; ++p)
            *(short8*)(Bs2 + (sr + p * 32) * PAD2 + sc) = breg[p];
        if (k0 + 64 < DIM_H) {
            #pragma unroll
            for (int p = 0; p < 10; ++p)
                breg[p] = *(const short8*)(WqkvT + (size_t)(sr + p * 32) * DIM_H + (k0 + 64) + sc);
        }
        __syncthreads();
        short8 af[2][2], bfr[5][2];
        #pragma unroll
        for (int m = 0; m < 2; ++m)
            #pragma unroll
            for (int kh = 0; kh < 2; ++kh)
                af[m][kh] = *(const short8*)(hS + (m * 16 + col16) * HP + k0 + kh * 32 + quad * 8);
        #pragma unroll
        for (int n = 0; n < 5; ++n)
            #pragma unroll
            for (int kh = 0; kh < 2; ++kh)
                bfr[n][kh] = *(const short8*)(Bs2 + (wave * 80 + n * 16 + col16) * PAD2 + kh * 32 + quad * 8);
        #pragma unroll
        for (int m = 0; m < 2; ++m)
            #pragma unroll
            for (int n = 0; n < 5; ++n)
                #pragma unroll
                for (int kh = 0; kh < 2; ++kh)
                    acc2[m][n] = MFMA16(af[m][kh], bfr[n][kh], acc2[m][n], 0, 0, 0);
        __syncthreads();
    }
    // epilogue 2: split -> qk fp32 [N][64], v fp8/bf16 [N][256]; bias read direct
    #pragma unroll
    for (int m = 0; m < 2; ++m)
        #pragma unroll
        for (int n = 0; n < 5; ++n) {
            int gc = wave * 80 + n * 16 + col16;
            float bia = (gc < DIM_C) ? bq[gc] : (gc < DIM_QK) ? bk[gc - DIM_C] : bv[gc - DIM_QK];
            #pragma unroll
            for (int r = 0; r < 4; ++r) {
                int gr = row0 + m * 16 + quad * 4 + r;
                if (gr >= N_NODES) continue;
                float v = acc2[m][n][r] + bia;
                if (gc < DIM_QK) {
                    qk[(size_t)gr * DIM_QK + gc] = v;
                } else {
#if V_FP8
                    int pk = __builtin_amdgcn_cvt_pk_fp8_f32(v * VSCALE, 0.f, 0, false);
                    ((unsigned char*)v_tab)[(size_t)gr * DIM_H + (gc - DIM_QK)] =
                        (unsigned char)(pk & 0xff);
#else
                    v_tab[(size_t)gr * DIM_H + (gc - DIM_QK)] = f2bf(v);
#endif
                }
            }
        }

    // ---- tail (off critical path): edge bucket-scatter + W1T/W2T transpose ----
    {
        const int stride = gridDim.x * 256;              // 80,128
        const int i0 = bid * 256 + tid;
        int s4[4], d4[4]; bool ok[4];
        #pragma unroll
        for (int t = 0; t < 4; ++t) {
            int e = i0 + t * stride;
            ok[t] = e < N_EDGES;
            s4[t] = ok[t] ? ei[e] : 0;
            d4[t] = ok[t] ? ei[N_EDGES + e] : 0;
        }
        #pragma unroll
        for (int t = 0; t < 4; ++t)
            if (ok[t]) {
                int slot = atomicAdd(&deg[s4[t]], 1);
                if (slot < MAXD) col[s4[t] * MAXD + slot] = d4[t];
            }
        for (int idx = i0; idx < DIM_CAT * DIM_H; idx += stride) {   // W1[512][256]
            int k = idx >> 8, n = idx & 255;
            W1T[n * DIM_CAT + k] = f2bf(W1[idx]);
        }
        for (int idx = i0; idx < DIM_H * DIM_OUT; idx += stride) {   // W2[256][64]
            int k = idx >> 6, n = idx & 63;
            W2T[n * DIM_H + k] = f2bf(W2[idx]);
        }
    }
}

// ---------------- fused per-row attention: dedup + softmax + weighted v-gather --------
// One wave per row, 4 rows per block (2500 blocks). Dedup now uses 4-wide LDS reads
// (<=8 independent int4 loads) instead of the ~31-deep serial __shfl chain.
__global__ __launch_bounds__(256)
void attn_row(const float* __restrict__ qk, const unsigned short* __restrict__ v_tab,
              const int* __restrict__ deg, const int* __restrict__ col,
              unsigned short* __restrict__ cat_bf) {
    __shared__ alignas(16) int dstS[4][MAXD];
    __shared__ float wS[4][MAXD];
    __shared__ float qS[4][DIM_C];
    const int wave = threadIdx.x >> 6;
    const int lane = threadIdx.x & 63;
    const int row = blockIdx.x * 4 + wave;   // grid is exactly N_NODES/4
    int d = deg[row];
    if (d > MAXD) d = MAXD;
    const int* crow = col + (size_t)row * MAXD;

    for (int p = lane; p < d; p += 64) dstS[wave][p] = crow[p];
    if (lane < DIM_C) qS[wave][lane] = qk[(size_t)row * DIM_QK + lane];
    __syncthreads();

    float mysum = 0.f;
    if (d <= 64) {
        int mydst = (lane < d) ? dstS[wave][lane] : -1;
        // dedup: first instance wins. 4-wide LDS compare against entries j < lane.
        bool dup = false;
        {
            const int4* ds4 = (const int4*)(&dstS[wave][0]);
            const int lim = (lane < d) ? lane : 0;
            for (int j0 = 0; j0 < lim; j0 += 4) {
                int4 v = ds4[j0 >> 2];
                dup = dup || (v.x == mydst)
                   || (j0 + 1 < lim && v.y == mydst)
                   || (j0 + 2 < lim && v.z == mydst)
                   || (j0 + 3 < lim && v.w == mydst);
            }
        }
        float w = 0.f;
        if (lane < d && !dup) {
            const float4* kp = (const float4*)(qk + (size_t)mydst * DIM_QK + DIM_C);
            float s = 0.f;
            #pragma unroll
            for (int i = 0; i < DIM_C / 4; ++i) {
                float4 b = kp[i];
                s += qS[wave][4 * i + 0] * b.x + qS[wave][4 * i + 1] * b.y
                   + qS[wave][4 * i + 2] * b.z + qS[wave][4 * i + 3] * b.w;
            }
            w = expf(s * SCALE);
        }
        wS[wave][lane] = w;
        mysum = w;
    } else {
        for (int p = lane; p < d; p += 64) {
            int mydst = dstS[wave][p];
            bool dup = false;
            for (int j = 0; j < p; ++j) dup = dup || (dstS[wave][j] == mydst);
            float w = 0.f;
            if (!dup) {
                const float4* kp = (const float4*)(qk + (size_t)mydst * DIM_QK + DIM_C);
                float s = 0.f;
                #pragma unroll
                for (int i = 0; i < DIM_C / 4; ++i) {
                    float4 b = kp[i];
                    s += qS[wave][4 * i + 0] * b.x + qS[wave][4 * i + 1] * b.y
                       + qS[wave][4 * i + 2] * b.z + qS[wave][4 * i + 3] * b.w;
                }
                w = expf(s * SCALE);
            }
            wS[wave][p] = w;
            mysum += w;
        }
    }
    #pragma unroll
    for (int off = 32; off; off >>= 1) mysum += __shfl_down(mysum, off, 64);
    float total = __shfl(mysum, 0, 64);
#if V_FP8
    float inv = (d > 0 && total > 0.f) ? 1.0f / (total * VSCALE) : 0.f;
#else
    float inv = (d > 0 && total > 0.f) ? 1.0f / total : 0.f;
#endif
    __syncthreads();

    float4 acc = make_float4(0.f, 0.f, 0.f, 0.f);
#if V_FP8
    const uint32_t* vb = (const uint32_t*)v_tab;     // fp8 row = 64 dwords
#else
    const uint2* vb = (const uint2*)v_tab;           // bf16 row = 64 uint2
#endif
    for (int p0 = 0; p0 < d; p0 += 16) {
        int j[16]; float w[16];
        #pragma unroll
        for (int t = 0; t < 16; ++t) {
            int idx = p0 + t;
            bool in = idx < d;
            j[t] = in ? dstS[wave][idx] : 0;        // pad: row 0 (L2-hot), weight 0
            w[t] = in ? wS[wave][idx] : 0.f;
        }
#if V_FP8
        uint32_t r[16];
        #pragma unroll
        for (int t = 0; t < 16; ++t) r[t] = vb[(size_t)j[t] * 64 + lane];
        #pragma unroll
        for (int t = 0; t < 16; ++t) {
            floatx2 lo = __builtin_amdgcn_cvt_pk_f32_fp8(r[t], false);
            floatx2 hi = __builtin_amdgcn_cvt_pk_f32_fp8(r[t], true);
            acc.x += w[t] * lo.x; acc.y += w[t] * lo.y;
            acc.z += w[t] * hi.x; acc.w += w[t] * hi.y;
        }
#else
        uint2 r[16];
        #pragma unroll
        for (int t = 0; t < 16; ++t) r[t] = vb[(size_t)j[t] * 64 + lane];
        #pragma unroll
        for (int t = 0; t < 16; ++t) {
            acc.x += w[t] * bf2f_lo(r[t].x);
            acc.y += w[t] * bf2f_hi(r[t].x);
            acc.z += w[t] * bf2f_lo(r[t].y);
            acc.w += w[t] * bf2f_hi(r[t].y);
        }
#endif
    }
    acc.x *= inv; acc.y *= inv; acc.z *= inv; acc.w *= inv;
    uint2 o;
    o.x = (uint32_t)f2bf(acc.x) | ((uint32_t)f2bf(acc.y) << 16);
    o.y = (uint32_t)f2bf(acc.z) | ((uint32_t)f2bf(acc.w) << 16);
    *(uint2*)(cat_bf + (size_t)row * DIM_CAT + DIM_H + lane * 4) = o;
}

// ---------------- fused W1(relu) + W2 GEMM, BM=32, K-step 64, REG-PREFETCH ------------
// Phase A: 8 k-steps of 64 with next-tile loads issued under current MFMA.
// Phase B: z @ W2T^T from LDS (Ts aliases Bs), K=256, fully unrolled.
__global__ __launch_bounds__(256)
void gemm_w1w2(const unsigned short* __restrict__ cat, const unsigned short* __restrict__ W1T,
               const float* __restrict__ b1, const unsigned short* __restrict__ W2T,
               const float* __restrict__ b2, float* __restrict__ out, int M)
{
    constexpr int TP = 260;   // Ts row stride (bf16)
    __shared__ short As[32 * PAD2];                //  4,608 B
    __shared__ short BsTs[256 * PAD2];             // 36,864 B: Bs; Ts (32*260*2=16,640) aliases
    short* Bs = BsTs;
    short* Ts = BsTs;
    const int tid   = threadIdx.x;
    const int wave  = tid >> 6;
    const int lane  = tid & 63;
    const int quad  = lane >> 4;
    const int col16 = lane & 15;
    const int row0  = blockIdx.x * 32;

    const int sr = tid >> 3;          // 0..31
    const int sc = (tid & 7) * 8;     // 16B k-chunk, 0..56
    const int gr_s = row0 + sr;

    // prologue: issue k0=0 tile loads
    short8 areg = {};
    if (gr_s < M) areg = *(const short8*)(cat + (size_t)gr_s * DIM_CAT + sc);
    short8 breg[8];
    #pragma unroll
    for (int p = 0; p < 8; ++p)
        breg[p] = *(const short8*)(W1T + (size_t)(sr + p * 32) * DIM_CAT + sc);

    // ---- phase A: z = relu(cat @ W1T^T + b1), 32 rows x 256 cols, K=512 (8 steps) ----
    floatx4 acc[2][4] = {};
    #pragma unroll
    for (int k0 = 0; k0 < DIM_CAT; k0 += 64) {
        *(short8*)(As + sr * PAD2 + sc) = areg;
        #pragma unroll
        for (int p = 0; p < 8; ++p)
            *(short8*)(Bs + (sr + p * 32) * PAD2 + sc) = breg[p];
        if (k0 + 64 < DIM_CAT) {   // prefetch next tile (hidden under MFMA below)
            areg = short8{};
            if (gr_s < M) areg = *(const short8*)(cat + (size_t)gr_s * DIM_CAT + (k0 + 64) + sc);
            #pragma unroll
            for (int p = 0; p < 8; ++p)
                breg[p] = *(const short8*)(W1T + (size_t)(sr + p * 32) * DIM_CAT + (k0 + 64) + sc);
        }
        __syncthreads();
        short8 af[2][2], bfr[4][2];
        #pragma unroll
        for (int m = 0; m < 2; ++m)
            #pragma unroll
            for (int kh = 0; kh < 2; ++kh)
                af[m][kh] = *(const short8*)(As + (m * 16 + col16) * PAD2 + kh * 32 + quad * 8);
        #pragma unroll
        for (int n = 0; n < 4; ++n)
            #pragma unroll
            for (int kh = 0; kh < 2; ++kh)
                bfr[n][kh] = *(const short8*)(Bs + (wave * 64 + n * 16 + col16) * PAD2 + kh * 32 + quad * 8);
        #pragma unroll
        for (int m = 0; m < 2; ++m)
            #pragma unroll
            for (int n = 0; n < 4; ++n)
                #pragma unroll
                for (int kh = 0; kh < 2; ++kh)
                    acc[m][n] = MFMA16(af[m][kh], bfr[n][kh], acc[m][n], 0, 0, 0);
        __syncthreads();   // Bs reads done before next staging / Ts overwrite
    }

    // epilogue A: bias + relu -> bf16 z tile in Ts (aliases Bs; safe after final barrier)
    #pragma unroll
    for (int m = 0; m < 2; ++m)
        #pragma unroll
        for (int n = 0; n < 4; ++n) {
            int gc = wave * 64 + n * 16 + col16;
            float bia = b1[gc];
            #pragma unroll
            for (int r = 0; r < 4; ++r) {
                int lr = m * 16 + quad * 4 + r;
                Ts[lr * TP + gc] = (short)f2bf(fmaxf(acc[m][n][r] + bia, 0.f));
            }
        }
    __syncthreads();

    // ---- phase B: out = z @ W2T^T + b2, K=256; wave owns cols [wave*16, wave*16+16) ----
    floatx4 acc2[2] = {};
    #pragma unroll
    for (int k0 = 0; k0 < DIM_H; k0 += 32) {
        short8 b = *(const short8*)(W2T + (size_t)(wave * 16 + col16) * DIM_H + k0 + quad * 8);
        #pragma unroll
        for (int m = 0; m < 2; ++m) {
            short8 a = *(const short8*)(Ts + (m * 16 + col16) * TP + k0 + quad * 8);
            acc2[m] = MFMA16(a, b, acc2[m], 0, 0, 0);
        }
    }
    #pragma unroll
    for (int m = 0; m < 2; ++m) {
        int gc = wave * 16 + col16;
        float bia = b2[gc];
        #pragma unroll
        for (int r = 0; r < 4; ++r) {
            int gr = row0 + m * 16 + quad * 4 + r;
            if (gr < M) out[(size_t)gr * DIM_OUT + gc] = acc2[m][r] + bia;
        }
    }
}

// ---------------- launcher: 4 dispatches ----------------
extern "C" void kernel_launch(void* const* d_in, const int* in_sizes, int n_in,
                              void* d_out, int out_size, void* d_ws, size_t ws_size,
                              hipStream_t stream) {
    (void)in_sizes; (void)n_in; (void)out_size; (void)ws_size;
    const float* x    = (const float*)d_in[0];
    const int*   ei   = (const int*)d_in[1];
    const float* W_in = (const float*)d_in[2];
    const float* b_in = (const float*)d_in[3];
    const float* Wq   = (const float*)d_in[4];
    const float* bq   = (const float*)d_in[5];
    const float* Wk   = (const float*)d_in[6];
    const float* bk   = (const float*)d_in[7];
    const float* Wv   = (const float*)d_in[8];
    const float* bv   = (const float*)d_in[9];
    const float* W1   = (const float*)d_in[10];
    const float* b1   = (const float*)d_in[11];
    const float* W2   = (const float*)d_in[12];
    const float* b2   = (const float*)d_in[13];
    float* out = (float*)d_out;

    uint32_t* ws      = (uint32_t*)d_ws;
    int*      deg     = (int*)(ws + OFF_DEG);
    int*      col     = (int*)(ws + OFF_COL);
    float*    qk      = (float*)(ws + OFF_QK);
    unsigned short* v_tab  = (unsigned short*)(ws + OFF_VT);
    unsigned short* cat_bf = (unsigned short*)(ws + OFF_CATBF);
    unsigned short* WinT   = (unsigned short*)(ws + OFF_WINT);
    unsigned short* WqkvT  = (unsigned short*)(ws + OFF_WQKVT);
    unsigned short* W1T    = (unsigned short*)(ws + OFF_W1T);
    unsigned short* W2T    = (unsigned short*)(ws + OFF_W2T);

    // 1) minimal blocking prep: deg zero + WinT/WqkvT transpose
    prep_w<<<256, 256, 0, stream>>>(W_in, Wq, Wk, Wv, deg, WinT, WqkvT);
    // 2) fused h-GEMM + qkv-GEMM, reg-prefetch pipeline (+scatter/W1T/W2T tail), 313 blocks
    gemm12<<<(N_NODES + 31) / 32, 256, 0, stream>>>(
        x, ei, WinT, b_in, WqkvT, bq, bk, bv, W1, W2,
        deg, col, cat_bf, qk, v_tab, W1T, W2T);
    // 3) fused sparse attention (LDS dedup + softmax + v-gather)
    attn_row<<<N_NODES / 4, 256, 0, stream>>>(qk, v_tab, deg, col, cat_bf);
    // 4) out = relu(cat@W1+b1)@W2 + b2, reg-prefetch pipeline, 313 blocks
    gemm_w1w2<<<(N_NODES + 31) / 32, 256, 0, stream>>>(
        cat_bf, W1T, b1, W2T, b2, out, N_NODES);
}